// Round 1
// baseline (2842.637 us; speedup 1.0000x reference)
//
#include <hip/hip_runtime.h>
#include <hip/hip_bf16.h>

// Problem constants (match reference)
constexpr int NN  = 65536;           // nodes
constexpr int EE  = 262144;          // edges before self loops
constexpr int E2  = EE + NN;         // 327680 edges with self loops
constexpr int BB  = 2048;            // graphs
constexpr int HH  = 4;               // heads
constexpr int DD  = 192;             // per-head dim
constexpr int HD  = 768;             // hidden
constexpr int LL  = 2;               // layers
constexpr float EPS = 1e-5f;
constexpr float SLOPE = 0.2f;

// ---------------------------------------------------------------------------
// utility: zero fill
__global__ void zero_k(float* __restrict__ p, int n) {
    int i = blockIdx.x * 256 + threadIdx.x;
    if (i < n) p[i] = 0.f;
}

// ---------------------------------------------------------------------------
// GEMM: C[M,768] = A[M,768] @ Bw[768,768] (+ optional bias[768])
// tile 128x64, K-step 16, 256 threads, 8x4 per thread
__global__ __launch_bounds__(256) void gemm_k(
    const float* __restrict__ A, const float* __restrict__ Bw,
    float* __restrict__ C, const float* __restrict__ bias, int M)
{
    constexpr int K = HD, NO = HD;
    __shared__ float As[16][132];   // [k][m], stride 132 -> conflict-light
    __shared__ float Bs[16][64];

    int tid = threadIdx.x;
    int tx = tid & 15;      // 0..15 col group (4 cols each)
    int ty = tid >> 4;      // 0..15 row group (8 rows each)
    int bm = blockIdx.y * 128;
    int bn = blockIdx.x * 64;

    int lm = tid >> 2;            // 0..63 (A row within tile, +64 rep)
    int lk = (tid & 3) << 2;      // 0,4,8,12
    int bk = tid >> 4;            // 0..15 (B k-row)
    int bc = (tid & 15) << 2;     // B col (float4)

    float acc[8][4];
    #pragma unroll
    for (int i = 0; i < 8; i++)
        #pragma unroll
        for (int j = 0; j < 4; j++) acc[i][j] = 0.f;

    for (int k0 = 0; k0 < K; k0 += 16) {
        #pragma unroll
        for (int r = 0; r < 2; r++) {
            int m = lm + r * 64;
            float4 av = *(const float4*)&A[(size_t)(bm + m) * K + k0 + lk];
            As[lk + 0][m] = av.x; As[lk + 1][m] = av.y;
            As[lk + 2][m] = av.z; As[lk + 3][m] = av.w;
        }
        float4 bv4 = *(const float4*)&Bw[(size_t)(k0 + bk) * NO + bn + bc];
        *(float4*)&Bs[bk][bc] = bv4;
        __syncthreads();
        #pragma unroll
        for (int k = 0; k < 16; k++) {
            float a[8];
            #pragma unroll
            for (int i = 0; i < 8; i++) a[i] = As[k][ty * 8 + i];
            float4 b = *(const float4*)&Bs[k][tx * 4];
            #pragma unroll
            for (int i = 0; i < 8; i++) {
                acc[i][0] += a[i] * b.x; acc[i][1] += a[i] * b.y;
                acc[i][2] += a[i] * b.z; acc[i][3] += a[i] * b.w;
            }
        }
        __syncthreads();
    }
    float4 badd = make_float4(0.f, 0.f, 0.f, 0.f);
    if (bias) badd = *(const float4*)&bias[bn + tx * 4];
    #pragma unroll
    for (int i = 0; i < 8; i++) {
        int row = bm + ty * 8 + i;
        float4 o;
        o.x = acc[i][0] + badd.x; o.y = acc[i][1] + badd.y;
        o.z = acc[i][2] + badd.z; o.w = acc[i][3] + badd.w;
        *(float4*)&C[(size_t)row * NO + bn + tx * 4] = o;
    }
}

// ---------------------------------------------------------------------------
// per-node attention logits: asrc[n,h] = dot(xw[n,h,:], att_src[h,:])
__global__ __launch_bounds__(256) void alpha_k(
    const float* __restrict__ xw,
    const float* __restrict__ asl, const float* __restrict__ adl,
    float* __restrict__ asrc, float* __restrict__ adst)
{
    int n = blockIdx.x, t = threadIdx.x;
    int head = t >> 6, lane = t & 63;
    const float* row = xw + (size_t)n * HD + head * DD;
    const float* a1 = asl + head * DD;
    const float* a2 = adl + head * DD;
    float s1 = 0.f, s2 = 0.f;
    #pragma unroll
    for (int j = 0; j < 3; j++) {      // DD = 192 = 3*64
        int d = lane + 64 * j;
        float v = row[d];
        s1 += v * a1[d]; s2 += v * a2[d];
    }
    #pragma unroll
    for (int off = 32; off > 0; off >>= 1) {
        s1 += __shfl_down(s1, off, 64);
        s2 += __shfl_down(s2, off, 64);
    }
    if (lane == 0) {
        asrc[(size_t)n * HH + head] = s1;
        adst[(size_t)n * HH + head] = s2;
    }
}

// ---------------------------------------------------------------------------
// CSR build over dst
__global__ void hist_k(const int* __restrict__ ei, int* __restrict__ deg) {
    int e = blockIdx.x * 256 + threadIdx.x;   // grid == E2 exactly
    int dst = (e < EE) ? ei[EE + e] : (e - EE);
    atomicAdd(&deg[dst], 1);
}

__global__ void scan1_k(const int* __restrict__ deg, int* __restrict__ incl,
                        int* __restrict__ blocksum) {
    __shared__ int s[256];
    int t = threadIdx.x, n = blockIdx.x * 256 + t;
    int v = deg[n];
    s[t] = v;
    for (int off = 1; off < 256; off <<= 1) {
        __syncthreads();
        int tmp = (t >= off) ? s[t - off] : 0;
        __syncthreads();
        s[t] += tmp;
    }
    incl[n] = s[t];
    if (t == 255) blocksum[blockIdx.x] = s[255];
}

__global__ void scan2_k(const int* __restrict__ blocksum, int* __restrict__ blockoff) {
    __shared__ int s[256];
    int t = threadIdx.x;
    int v = blocksum[t];
    s[t] = v;
    for (int off = 1; off < 256; off <<= 1) {
        __syncthreads();
        int tmp = (t >= off) ? s[t - off] : 0;
        __syncthreads();
        s[t] += tmp;
    }
    blockoff[t] = s[t] - v;   // exclusive
}

__global__ void scan3_k(const int* __restrict__ deg, const int* __restrict__ blockoff,
                        int* __restrict__ incl_cursor, int* __restrict__ rowstart) {
    int t = threadIdx.x, n = blockIdx.x * 256 + t;
    int rs = blockoff[blockIdx.x] + incl_cursor[n] - deg[n];
    rowstart[n] = rs;
    incl_cursor[n] = rs;       // becomes the fill cursor
    if (n == 0) rowstart[NN] = E2;
}

__global__ void fill_k(const int* __restrict__ ei, int* __restrict__ cursor,
                       int* __restrict__ csr_src, int* __restrict__ csr_eid) {
    int e = blockIdx.x * 256 + threadIdx.x;
    int src = (e < EE) ? ei[e] : (e - EE);
    int dst = (e < EE) ? ei[EE + e] : (e - EE);
    int pos = atomicAdd(&cursor[dst], 1);
    csr_src[pos] = src;
    csr_eid[pos] = e;
}

// ---------------------------------------------------------------------------
// edge kernel: ex[e,h] = exp(leaky_relu(asrc[src,h]+adst[dst,h]))
// (no max-shift: logits are O(1), softmax is shift-invariant)
__global__ void edge_k(const int* __restrict__ ei,
                       const float4* __restrict__ asrc, const float4* __restrict__ adst,
                       float4* __restrict__ ex, float* __restrict__ denom) {
    int e = blockIdx.x * 256 + threadIdx.x;
    int src = (e < EE) ? ei[e] : (e - EE);
    int dst = (e < EE) ? ei[EE + e] : (e - EE);
    float4 a = asrc[src], b = adst[dst];
    float4 v;
    float t0 = a.x + b.x; t0 = (t0 > 0.f) ? t0 : SLOPE * t0; v.x = expf(t0);
    float t1 = a.y + b.y; t1 = (t1 > 0.f) ? t1 : SLOPE * t1; v.y = expf(t1);
    float t2 = a.z + b.z; t2 = (t2 > 0.f) ? t2 : SLOPE * t2; v.z = expf(t2);
    float t3 = a.w + b.w; t3 = (t3 > 0.f) ? t3 : SLOPE * t3; v.w = expf(t3);
    ex[e] = v;
    atomicAdd(&denom[(size_t)dst * 4 + 0], v.x);
    atomicAdd(&denom[(size_t)dst * 4 + 1], v.y);
    atomicAdd(&denom[(size_t)dst * 4 + 2], v.z);
    atomicAdd(&denom[(size_t)dst * 4 + 3], v.w);
}

// ---------------------------------------------------------------------------
// block reduce over 256 threads (4 waves)
__device__ __forceinline__ float blk_sum(float v, float* sm) {
    #pragma unroll
    for (int off = 32; off > 0; off >>= 1) v += __shfl_down(v, off, 64);
    __syncthreads();                       // protect sm reuse across calls
    if ((threadIdx.x & 63) == 0) sm[threadIdx.x >> 6] = v;
    __syncthreads();
    return sm[0] + sm[1] + sm[2] + sm[3];
}

// aggregation + bias + LayerNorm + ReLU + residual, one block per node
__global__ __launch_bounds__(256) void agg_k(
    const float* __restrict__ xw, const float4* __restrict__ ex,
    const float4* __restrict__ denom, const int* __restrict__ rowstart,
    const int* __restrict__ csr_src, const int* __restrict__ csr_eid,
    const float* __restrict__ bias_l, const float* __restrict__ gamma_l,
    const float* __restrict__ beta_l, const float* __restrict__ h_in,
    float* __restrict__ h_out)
{
    int i = blockIdx.x, t = threadIdx.x;
    __shared__ int   s_src[64];
    __shared__ float s_w[64][4];
    __shared__ float s_red[4];

    int r0 = rowstart[i], r1 = rowstart[i + 1];
    float4 dn = denom[i];
    float inv0 = 1.f / dn.x, inv1 = 1.f / dn.y, inv2 = 1.f / dn.z, inv3 = 1.f / dn.w;

    int c0 = t, c1 = t + 256, c2 = t + 512;
    int h0 = c0 / DD, h1 = c1 / DD, h2 = c2 / DD;
    float a0 = 0.f, a1 = 0.f, a2 = 0.f;

    for (int base = r0; base < r1; base += 64) {
        int cnt = min(64, r1 - base);
        if (t < cnt) {
            s_src[t] = csr_src[base + t];
            float4 w = ex[csr_eid[base + t]];
            s_w[t][0] = w.x * inv0; s_w[t][1] = w.y * inv1;
            s_w[t][2] = w.z * inv2; s_w[t][3] = w.w * inv3;
        }
        __syncthreads();
        for (int e = 0; e < cnt; e++) {
            const float* row = xw + (size_t)s_src[e] * HD;
            a0 += s_w[e][h0] * row[c0];
            a1 += s_w[e][h1] * row[c1];
            a2 += s_w[e][h2] * row[c2];
        }
        __syncthreads();
    }

    float v0 = a0 + bias_l[c0], v1 = a1 + bias_l[c1], v2 = a2 + bias_l[c2];
    float mean = blk_sum(v0 + v1 + v2, s_red) * (1.f / (float)HD);
    float d0 = v0 - mean, d1 = v1 - mean, d2 = v2 - mean;
    float var = blk_sum(d0 * d0 + d1 * d1 + d2 * d2, s_red) * (1.f / (float)HD);
    float rs = rsqrtf(var + EPS);

    const float* hrow = h_in + (size_t)i * HD;
    float* orow = h_out + (size_t)i * HD;
    float o0 = fmaxf(d0 * rs * gamma_l[c0] + beta_l[c0], 0.f) + hrow[c0];
    float o1 = fmaxf(d1 * rs * gamma_l[c1] + beta_l[c1], 0.f) + hrow[c1];
    float o2 = fmaxf(d2 * rs * gamma_l[c2] + beta_l[c2], 0.f) + hrow[c2];
    orow[c0] = o0; orow[c1] = o1; orow[c2] = o2;
}

// ---------------------------------------------------------------------------
// global mean pool per graph (batch_vec is sorted; binary search bounds)
__global__ __launch_bounds__(256) void pool_k(
    const float* __restrict__ h, const int* __restrict__ bv, float* __restrict__ hg)
{
    int g = blockIdx.x, t = threadIdx.x;
    int lo = 0, hi = NN;
    while (lo < hi) { int mid = (lo + hi) >> 1; if (bv[mid] < g) lo = mid + 1; else hi = mid; }
    int start = lo;
    hi = NN;
    while (lo < hi) { int mid = (lo + hi) >> 1; if (bv[mid] < g + 1) lo = mid + 1; else hi = mid; }
    int end = lo;
    float a0 = 0.f, a1 = 0.f, a2 = 0.f;
    for (int n = start; n < end; n++) {
        const float* row = h + (size_t)n * HD;
        a0 += row[t]; a1 += row[t + 256]; a2 += row[t + 512];
    }
    float sc = 1.f / fmaxf((float)(end - start), 1.f);
    float* o = hg + (size_t)g * HD;
    o[t] = a0 * sc; o[t + 256] = a1 * sc; o[t + 512] = a2 * sc;
}

// ---------------------------------------------------------------------------
extern "C" void kernel_launch(void* const* d_in, const int* in_sizes, int n_in,
                              void* d_out, int out_size, void* d_ws, size_t ws_size,
                              hipStream_t stream)
{
    (void)in_sizes; (void)n_in; (void)out_size;
    const float* x       = (const float*)d_in[0];
    const int*   ei      = (const int*)d_in[1];
    const int*   bv      = (const int*)d_in[2];
    const float* W       = (const float*)d_in[3];
    const float* att_src = (const float*)d_in[4];
    const float* att_dst = (const float*)d_in[5];
    const float* bias    = (const float*)d_in[6];
    const float* gamma   = (const float*)d_in[7];
    const float* beta    = (const float*)d_in[8];
    const float* out_w   = (const float*)d_in[9];
    const float* out_b   = (const float*)d_in[10];
    float* out = (float*)d_out;

    char* p = (char*)d_ws;
    size_t off = 0;
    auto take = [&](size_t bytes) -> char* {
        char* r = p + off;
        off = (off + bytes + 255) & ~(size_t)255;
        return r;
    };
    float* xw       = (float*)take((size_t)NN * HD * 4);
    float* asrc     = (float*)take((size_t)NN * HH * 4);
    float* adst     = (float*)take((size_t)NN * HH * 4);
    float* ex       = (float*)take((size_t)E2 * HH * 4);
    float* denom    = (float*)take((size_t)NN * HH * 4);
    int*   deg      = (int*)take((size_t)NN * 4);
    int*   rowstart = (int*)take((size_t)(NN + 1) * 4);
    int*   cursor   = (int*)take((size_t)NN * 4);
    int*   blocksum = (int*)take(256 * 4);
    int*   blockoff = (int*)take(256 * 4);
    int*   csr_src  = (int*)take((size_t)E2 * 4);
    int*   csr_eid  = (int*)take((size_t)E2 * 4);
    float* hg       = (float*)take((size_t)BB * HD * 4);
    // h buffer: prefer ws; fall back to aliasing the x input (harness restores
    // inputs before every launch, and the in-place row update is block-local).
    float* h;
    if (ws_size >= off + (size_t)NN * HD * 4) h = (float*)take((size_t)NN * HD * 4);
    else                                      h = (float*)d_in[0];

    const int EB = E2 / 256;   // 1280, exact

    // ---- CSR build (topology only, once) ----
    zero_k<<<NN / 256, 256, 0, stream>>>((float*)deg, NN);
    hist_k<<<EB, 256, 0, stream>>>(ei, deg);
    scan1_k<<<NN / 256, 256, 0, stream>>>(deg, cursor, blocksum);
    scan2_k<<<1, 256, 0, stream>>>(blocksum, blockoff);
    scan3_k<<<NN / 256, 256, 0, stream>>>(deg, blockoff, cursor, rowstart);
    fill_k<<<EB, 256, 0, stream>>>(ei, cursor, csr_src, csr_eid);

    // ---- layers ----
    for (int l = 0; l < LL; l++) {
        const float* h_in = (l == 0) ? x : h;
        gemm_k<<<dim3(HD / 64, NN / 128), 256, 0, stream>>>(
            h_in, W + (size_t)l * HD * HD, xw, nullptr, NN);
        alpha_k<<<NN, 256, 0, stream>>>(xw, att_src + (size_t)l * HH * DD,
                                        att_dst + (size_t)l * HH * DD, asrc, adst);
        zero_k<<<NN * HH / 256, 256, 0, stream>>>(denom, NN * HH);
        edge_k<<<EB, 256, 0, stream>>>(ei, (const float4*)asrc, (const float4*)adst,
                                       (float4*)ex, denom);
        agg_k<<<NN, 256, 0, stream>>>(xw, (const float4*)ex, (const float4*)denom,
                                      rowstart, csr_src, csr_eid,
                                      bias + (size_t)l * HD, gamma + (size_t)l * HD,
                                      beta + (size_t)l * HD, h_in, h);
    }

    // ---- pooling + output projection ----
    pool_k<<<BB, 256, 0, stream>>>(h, bv, hg);
    gemm_k<<<dim3(HD / 64, BB / 128), 256, 0, stream>>>(hg, out_w, out, out_b, BB);
}

// Round 2
// 1371.740 us; speedup vs baseline: 2.0723x; 2.0723x over previous
//
#include <hip/hip_runtime.h>
#include <hip/hip_bf16.h>

// Problem constants (match reference)
constexpr int NN  = 65536;           // nodes
constexpr int EE  = 262144;          // edges before self loops
constexpr int E2  = EE + NN;         // 327680 edges with self loops
constexpr int BB  = 2048;            // graphs
constexpr int HH  = 4;               // heads
constexpr int DD  = 192;             // per-head dim
constexpr int HD  = 768;             // hidden
constexpr int LL  = 2;               // layers
constexpr float EPS = 1e-5f;
constexpr float SLOPE = 0.2f;

typedef __attribute__((ext_vector_type(8))) short short8;   // 8 bf16 (4 VGPRs)
typedef __attribute__((ext_vector_type(4))) float f32x4;    // MFMA C/D

// ---------------------------------------------------------------------------
__global__ void zero_k(float* __restrict__ p, int n) {
    int i = blockIdx.x * 256 + threadIdx.x;
    if (i < n) p[i] = 0.f;
}

// fp32 -> bf16 convert (4 elements/thread)
__global__ void conv_k(const float4* __restrict__ src, __hip_bfloat16* __restrict__ dst, int n4) {
    int i = blockIdx.x * 256 + threadIdx.x;
    if (i >= n4) return;
    float4 v = src[i];
    __hip_bfloat16* o = dst + (size_t)i * 4;
    o[0] = __float2bfloat16(v.x); o[1] = __float2bfloat16(v.y);
    o[2] = __float2bfloat16(v.z); o[3] = __float2bfloat16(v.w);
}

// W [768,768] row-major [k][n] fp32  ->  Wt [n][k] bf16 (transpose + convert)
__global__ __launch_bounds__(256) void wconv_k(const float* __restrict__ W,
                                               __hip_bfloat16* __restrict__ Wt) {
    __shared__ float tile[32][33];
    int bx = blockIdx.x * 32;   // n base
    int by = blockIdx.y * 32;   // k base
    int tx = threadIdx.x & 31, ty = threadIdx.x >> 5;   // ty 0..7
    #pragma unroll
    for (int r = 0; r < 32; r += 8)
        tile[ty + r][tx] = W[(size_t)(by + ty + r) * HD + bx + tx];
    __syncthreads();
    #pragma unroll
    for (int r = 0; r < 32; r += 8)
        Wt[(size_t)(bx + ty + r) * HD + by + tx] = __float2bfloat16(tile[tx][ty + r]);
}

// ---------------------------------------------------------------------------
// bf16 MFMA GEMM: C[M,768] = A[M,768] @ Bt[768,768]^T (+ optional bias)
// A, Bt bf16 row-major [row][k]; C fp32. Tile 128x128, BK=32, 256 thr (4 waves),
// each wave 4x4 grid of 16x16x32 MFMA. global_load_lds width-16 staging (m97).
__device__ __forceinline__ void load16_lds(const void* g, void* l) {
    __builtin_amdgcn_global_load_lds(
        (const __attribute__((address_space(1))) unsigned int*)g,
        (__attribute__((address_space(3))) unsigned int*)l, 16, 0, 0);
}

__global__ __launch_bounds__(256) void gemm_bf16_k(
    const __hip_bfloat16* __restrict__ A, const __hip_bfloat16* __restrict__ Bt,
    float* __restrict__ C, const float* __restrict__ bias)
{
    constexpr int K = HD;
    __shared__ __attribute__((aligned(16))) short As[128 * 32];
    __shared__ __attribute__((aligned(16))) short Bs[128 * 32];

    int tid  = threadIdx.x;
    int wave = tid >> 6, lane = tid & 63;
    int wy = wave >> 1, wx = wave & 1;          // wave quadrant (64x64)
    int m16 = lane & 15, quad = lane >> 4;      // MFMA fragment coords
    int bm = blockIdx.y * 128;
    int bn = blockIdx.x * 128;

    // staging positions: p = wave*128 + t*64 + lane -> chunk (row=p>>2, c=p&3)
    int p0 = wave * 128 + lane;                  // t=0
    int r0 = p0 >> 2, c0 = p0 & 3;
    int p1 = p0 + 64;                            // t=1
    int r1 = p1 >> 2, c1 = p1 & 3;

    const __hip_bfloat16* gA0 = A  + (size_t)(bm + r0) * K + c0 * 8;
    const __hip_bfloat16* gA1 = A  + (size_t)(bm + r1) * K + c1 * 8;
    const __hip_bfloat16* gB0 = Bt + (size_t)(bn + r0) * K + c0 * 8;
    const __hip_bfloat16* gB1 = Bt + (size_t)(bn + r1) * K + c1 * 8;

    f32x4 acc[4][4];
    #pragma unroll
    for (int i = 0; i < 4; i++)
        #pragma unroll
        for (int j = 0; j < 4; j++) acc[i][j] = (f32x4)0.f;

    const short8* Ac = (const short8*)As;
    const short8* Bc = (const short8*)Bs;

    for (int k0 = 0; k0 < K; k0 += 32) {
        load16_lds(gA0 + k0, &As[p0 * 8]);
        load16_lds(gA1 + k0, &As[p1 * 8]);
        load16_lds(gB0 + k0, &Bs[p0 * 8]);
        load16_lds(gB1 + k0, &Bs[p1 * 8]);
        __syncthreads();   // drains vmcnt(0): LDS tiles ready

        short8 a[4], b[4];
        #pragma unroll
        for (int i = 0; i < 4; i++)
            a[i] = Ac[(wy * 64 + i * 16 + m16) * 4 + quad];
        #pragma unroll
        for (int j = 0; j < 4; j++)
            b[j] = Bc[(wx * 64 + j * 16 + m16) * 4 + quad];
        #pragma unroll
        for (int i = 0; i < 4; i++)
            #pragma unroll
            for (int j = 0; j < 4; j++)
                acc[i][j] = __builtin_amdgcn_mfma_f32_16x16x32_bf16(a[i], b[j], acc[i][j], 0, 0, 0);
        __syncthreads();   // all ds_reads done before next staging overwrites
    }

    // epilogue: C/D layout col=lane&15, row=(lane>>4)*4+reg
    #pragma unroll
    for (int j = 0; j < 4; j++) {
        int col = bn + wx * 64 + j * 16 + m16;
        float badd = bias ? bias[col] : 0.f;
        #pragma unroll
        for (int i = 0; i < 4; i++) {
            int row0 = bm + wy * 64 + i * 16 + quad * 4;
            #pragma unroll
            for (int r = 0; r < 4; r++)
                C[(size_t)(row0 + r) * HD + col] = acc[i][j][r] + badd;
        }
    }
}

// ---------------------------------------------------------------------------
// per-node attention logits: asrc[n,h] = dot(xw[n,h,:], att_src[h,:])
__global__ __launch_bounds__(256) void alpha_k(
    const float* __restrict__ xw,
    const float* __restrict__ asl, const float* __restrict__ adl,
    float* __restrict__ asrc, float* __restrict__ adst)
{
    int n = blockIdx.x, t = threadIdx.x;
    int head = t >> 6, lane = t & 63;
    const float* row = xw + (size_t)n * HD + head * DD;
    const float* a1 = asl + head * DD;
    const float* a2 = adl + head * DD;
    float s1 = 0.f, s2 = 0.f;
    #pragma unroll
    for (int j = 0; j < 3; j++) {      // DD = 192 = 3*64
        int d = lane + 64 * j;
        float v = row[d];
        s1 += v * a1[d]; s2 += v * a2[d];
    }
    #pragma unroll
    for (int off = 32; off > 0; off >>= 1) {
        s1 += __shfl_down(s1, off, 64);
        s2 += __shfl_down(s2, off, 64);
    }
    if (lane == 0) {
        asrc[(size_t)n * HH + head] = s1;
        adst[(size_t)n * HH + head] = s2;
    }
}

// ---------------------------------------------------------------------------
// CSR build over dst
__global__ void hist_k(const int* __restrict__ ei, int* __restrict__ deg) {
    int e = blockIdx.x * 256 + threadIdx.x;   // grid == E2 exactly
    int dst = (e < EE) ? ei[EE + e] : (e - EE);
    atomicAdd(&deg[dst], 1);
}

__global__ void scan1_k(const int* __restrict__ deg, int* __restrict__ incl,
                        int* __restrict__ blocksum) {
    __shared__ int s[256];
    int t = threadIdx.x, n = blockIdx.x * 256 + t;
    int v = deg[n];
    s[t] = v;
    for (int off = 1; off < 256; off <<= 1) {
        __syncthreads();
        int tmp = (t >= off) ? s[t - off] : 0;
        __syncthreads();
        s[t] += tmp;
    }
    incl[n] = s[t];
    if (t == 255) blocksum[blockIdx.x] = s[255];
}

__global__ void scan2_k(const int* __restrict__ blocksum, int* __restrict__ blockoff) {
    __shared__ int s[256];
    int t = threadIdx.x;
    int v = blocksum[t];
    s[t] = v;
    for (int off = 1; off < 256; off <<= 1) {
        __syncthreads();
        int tmp = (t >= off) ? s[t - off] : 0;
        __syncthreads();
        s[t] += tmp;
    }
    blockoff[t] = s[t] - v;   // exclusive
}

__global__ void scan3_k(const int* __restrict__ deg, const int* __restrict__ blockoff,
                        int* __restrict__ incl_cursor, int* __restrict__ rowstart) {
    int t = threadIdx.x, n = blockIdx.x * 256 + t;
    int rs = blockoff[blockIdx.x] + incl_cursor[n] - deg[n];
    rowstart[n] = rs;
    incl_cursor[n] = rs;       // becomes the fill cursor
    if (n == 0) rowstart[NN] = E2;
}

__global__ void fill_k(const int* __restrict__ ei, int* __restrict__ cursor,
                       int* __restrict__ csr_src, int* __restrict__ csr_eid) {
    int e = blockIdx.x * 256 + threadIdx.x;
    int src = (e < EE) ? ei[e] : (e - EE);
    int dst = (e < EE) ? ei[EE + e] : (e - EE);
    int pos = atomicAdd(&cursor[dst], 1);
    csr_src[pos] = src;
    csr_eid[pos] = e;
}

// ---------------------------------------------------------------------------
// edge kernel: ex[e,h] = exp(leaky_relu(asrc[src,h]+adst[dst,h]))
// (no max-shift: logits are O(1), softmax is shift-invariant)
__global__ void edge_k(const int* __restrict__ ei,
                       const float4* __restrict__ asrc, const float4* __restrict__ adst,
                       float4* __restrict__ ex, float* __restrict__ denom) {
    int e = blockIdx.x * 256 + threadIdx.x;
    int src = (e < EE) ? ei[e] : (e - EE);
    int dst = (e < EE) ? ei[EE + e] : (e - EE);
    float4 a = asrc[src], b = adst[dst];
    float4 v;
    float t0 = a.x + b.x; t0 = (t0 > 0.f) ? t0 : SLOPE * t0; v.x = expf(t0);
    float t1 = a.y + b.y; t1 = (t1 > 0.f) ? t1 : SLOPE * t1; v.y = expf(t1);
    float t2 = a.z + b.z; t2 = (t2 > 0.f) ? t2 : SLOPE * t2; v.z = expf(t2);
    float t3 = a.w + b.w; t3 = (t3 > 0.f) ? t3 : SLOPE * t3; v.w = expf(t3);
    ex[e] = v;
    atomicAdd(&denom[(size_t)dst * 4 + 0], v.x);
    atomicAdd(&denom[(size_t)dst * 4 + 1], v.y);
    atomicAdd(&denom[(size_t)dst * 4 + 2], v.z);
    atomicAdd(&denom[(size_t)dst * 4 + 3], v.w);
}

// ---------------------------------------------------------------------------
__device__ __forceinline__ float blk_sum(float v, float* sm) {
    #pragma unroll
    for (int off = 32; off > 0; off >>= 1) v += __shfl_down(v, off, 64);
    __syncthreads();                       // protect sm reuse across calls
    if ((threadIdx.x & 63) == 0) sm[threadIdx.x >> 6] = v;
    __syncthreads();
    return sm[0] + sm[1] + sm[2] + sm[3];
}

// aggregation + bias + LayerNorm + ReLU + residual; writes fp32 h and bf16 h
__global__ __launch_bounds__(256) void agg_k(
    const float* __restrict__ xw, const float4* __restrict__ ex,
    const float4* __restrict__ denom, const int* __restrict__ rowstart,
    const int* __restrict__ csr_src, const int* __restrict__ csr_eid,
    const float* __restrict__ bias_l, const float* __restrict__ gamma_l,
    const float* __restrict__ beta_l, const float* __restrict__ h_in,
    float* __restrict__ h_out, __hip_bfloat16* __restrict__ hb_out)
{
    int i = blockIdx.x, t = threadIdx.x;
    __shared__ int   s_src[64];
    __shared__ float s_w[64][4];
    __shared__ float s_red[4];

    int r0 = rowstart[i], r1 = rowstart[i + 1];
    float4 dn = denom[i];
    float inv0 = 1.f / dn.x, inv1 = 1.f / dn.y, inv2 = 1.f / dn.z, inv3 = 1.f / dn.w;

    int c0 = t, c1 = t + 256, c2 = t + 512;
    int h0 = c0 / DD, h1 = c1 / DD, h2 = c2 / DD;
    float a0 = 0.f, a1 = 0.f, a2 = 0.f;

    for (int base = r0; base < r1; base += 64) {
        int cnt = min(64, r1 - base);
        if (t < cnt) {
            s_src[t] = csr_src[base + t];
            float4 w = ex[csr_eid[base + t]];
            s_w[t][0] = w.x * inv0; s_w[t][1] = w.y * inv1;
            s_w[t][2] = w.z * inv2; s_w[t][3] = w.w * inv3;
        }
        __syncthreads();
        for (int e = 0; e < cnt; e++) {
            const float* row = xw + (size_t)s_src[e] * HD;
            a0 += s_w[e][h0] * row[c0];
            a1 += s_w[e][h1] * row[c1];
            a2 += s_w[e][h2] * row[c2];
        }
        __syncthreads();
    }

    float v0 = a0 + bias_l[c0], v1 = a1 + bias_l[c1], v2 = a2 + bias_l[c2];
    float mean = blk_sum(v0 + v1 + v2, s_red) * (1.f / (float)HD);
    float d0 = v0 - mean, d1 = v1 - mean, d2 = v2 - mean;
    float var = blk_sum(d0 * d0 + d1 * d1 + d2 * d2, s_red) * (1.f / (float)HD);
    float rs = rsqrtf(var + EPS);

    const float* hrow = h_in + (size_t)i * HD;
    float* orow = h_out + (size_t)i * HD;
    __hip_bfloat16* brow = hb_out + (size_t)i * HD;
    float o0 = fmaxf(d0 * rs * gamma_l[c0] + beta_l[c0], 0.f) + hrow[c0];
    float o1 = fmaxf(d1 * rs * gamma_l[c1] + beta_l[c1], 0.f) + hrow[c1];
    float o2 = fmaxf(d2 * rs * gamma_l[c2] + beta_l[c2], 0.f) + hrow[c2];
    orow[c0] = o0; orow[c1] = o1; orow[c2] = o2;
    brow[c0] = __float2bfloat16(o0); brow[c1] = __float2bfloat16(o1);
    brow[c2] = __float2bfloat16(o2);
}

// ---------------------------------------------------------------------------
// global mean pool per graph -> bf16 hg (input to final MFMA GEMM)
__global__ __launch_bounds__(256) void pool_k(
    const float* __restrict__ h, const int* __restrict__ bv,
    __hip_bfloat16* __restrict__ hg)
{
    int g = blockIdx.x, t = threadIdx.x;
    int lo = 0, hi = NN;
    while (lo < hi) { int mid = (lo + hi) >> 1; if (bv[mid] < g) lo = mid + 1; else hi = mid; }
    int start = lo;
    hi = NN;
    while (lo < hi) { int mid = (lo + hi) >> 1; if (bv[mid] < g + 1) lo = mid + 1; else hi = mid; }
    int end = lo;
    float a0 = 0.f, a1 = 0.f, a2 = 0.f;
    for (int n = start; n < end; n++) {
        const float* row = h + (size_t)n * HD;
        a0 += row[t]; a1 += row[t + 256]; a2 += row[t + 512];
    }
    float sc = 1.f / fmaxf((float)(end - start), 1.f);
    __hip_bfloat16* o = hg + (size_t)g * HD;
    o[t]       = __float2bfloat16(a0 * sc);
    o[t + 256] = __float2bfloat16(a1 * sc);
    o[t + 512] = __float2bfloat16(a2 * sc);
}

// ---------------------------------------------------------------------------
extern "C" void kernel_launch(void* const* d_in, const int* in_sizes, int n_in,
                              void* d_out, int out_size, void* d_ws, size_t ws_size,
                              hipStream_t stream)
{
    (void)in_sizes; (void)n_in; (void)out_size;
    const float* x       = (const float*)d_in[0];
    const int*   ei      = (const int*)d_in[1];
    const int*   bv      = (const int*)d_in[2];
    const float* W       = (const float*)d_in[3];
    const float* att_src = (const float*)d_in[4];
    const float* att_dst = (const float*)d_in[5];
    const float* bias    = (const float*)d_in[6];
    const float* gamma   = (const float*)d_in[7];
    const float* beta    = (const float*)d_in[8];
    const float* out_w   = (const float*)d_in[9];
    const float* out_b   = (const float*)d_in[10];
    float* out = (float*)d_out;

    char* p = (char*)d_ws;
    size_t off = 0;
    auto take = [&](size_t bytes) -> char* {
        char* r = p + off;
        off = (off + bytes + 255) & ~(size_t)255;
        return r;
    };
    float* xw            = (float*)take((size_t)NN * HD * 4);
    __hip_bfloat16* hbf  = (__hip_bfloat16*)take((size_t)NN * HD * 2);  // bf16 A for gemm
    __hip_bfloat16* Wt   = (__hip_bfloat16*)take((size_t)HD * HD * 2);
    __hip_bfloat16* OWt  = (__hip_bfloat16*)take((size_t)HD * HD * 2);
    float* asrc     = (float*)take((size_t)NN * HH * 4);
    float* adst     = (float*)take((size_t)NN * HH * 4);
    float* ex       = (float*)take((size_t)E2 * HH * 4);
    float* denom    = (float*)take((size_t)NN * HH * 4);
    int*   deg      = (int*)take((size_t)NN * 4);
    int*   rowstart = (int*)take((size_t)(NN + 1) * 4);
    int*   cursor   = (int*)take((size_t)NN * 4);
    int*   blocksum = (int*)take(256 * 4);
    int*   blockoff = (int*)take(256 * 4);
    int*   csr_src  = (int*)take((size_t)E2 * 4);
    int*   csr_eid  = (int*)take((size_t)E2 * 4);
    __hip_bfloat16* hg = (__hip_bfloat16*)take((size_t)BB * HD * 2);
    // h buffer: prefer ws; fall back to aliasing the x input (harness restores
    // inputs before every launch, and the in-place row update is block-local).
    float* h;
    if (ws_size >= off + (size_t)NN * HD * 4) h = (float*)take((size_t)NN * HD * 4);
    else                                      h = (float*)d_in[0];

    const int EB = E2 / 256;   // 1280, exact

    // ---- CSR build (topology only, once) ----
    zero_k<<<NN / 256, 256, 0, stream>>>((float*)deg, NN);
    hist_k<<<EB, 256, 0, stream>>>(ei, deg);
    scan1_k<<<NN / 256, 256, 0, stream>>>(deg, cursor, blocksum);
    scan2_k<<<1, 256, 0, stream>>>(blocksum, blockoff);
    scan3_k<<<NN / 256, 256, 0, stream>>>(deg, blockoff, cursor, rowstart);
    fill_k<<<EB, 256, 0, stream>>>(ei, cursor, csr_src, csr_eid);

    // ---- bf16 conversions: x -> hbf (layer-0 A) ----
    conv_k<<<(NN * HD / 4 + 255) / 256, 256, 0, stream>>>((const float4*)x, hbf, NN * HD / 4);

    // ---- layers ----
    for (int l = 0; l < LL; l++) {
        const float* h_in = (l == 0) ? x : h;
        wconv_k<<<dim3(HD / 32, HD / 32), 256, 0, stream>>>(W + (size_t)l * HD * HD, Wt);
        gemm_bf16_k<<<dim3(HD / 128, NN / 128), 256, 0, stream>>>(hbf, Wt, xw, nullptr);
        alpha_k<<<NN, 256, 0, stream>>>(xw, att_src + (size_t)l * HH * DD,
                                        att_dst + (size_t)l * HH * DD, asrc, adst);
        zero_k<<<NN * HH / 256, 256, 0, stream>>>(denom, NN * HH);
        edge_k<<<EB, 256, 0, stream>>>(ei, (const float4*)asrc, (const float4*)adst,
                                       (float4*)ex, denom);
        agg_k<<<NN, 256, 0, stream>>>(xw, (const float4*)ex, (const float4*)denom,
                                      rowstart, csr_src, csr_eid,
                                      bias + (size_t)l * HD, gamma + (size_t)l * HD,
                                      beta + (size_t)l * HD, h_in, h, hbf);
    }

    // ---- pooling + output projection (bf16 MFMA) ----
    pool_k<<<BB, 256, 0, stream>>>(h, bv, hg);
    wconv_k<<<dim3(HD / 32, HD / 32), 256, 0, stream>>>(out_w, OWt);
    gemm_bf16_k<<<dim3(HD / 128, BB / 128), 256, 0, stream>>>(hg, OWt, out, out_b);
}

// Round 3
// 1122.750 us; speedup vs baseline: 2.5319x; 1.2218x over previous
//
#include <hip/hip_runtime.h>
#include <hip/hip_bf16.h>

// Problem constants (match reference)
constexpr int NN  = 65536;           // nodes
constexpr int EE  = 262144;          // edges before self loops
constexpr int E2  = EE + NN;         // 327680 edges with self loops
constexpr int BB  = 2048;            // graphs
constexpr int HH  = 4;               // heads
constexpr int DD  = 192;             // per-head dim
constexpr int HD  = 768;             // hidden
constexpr int LL  = 2;               // layers
constexpr float EPS = 1e-5f;
constexpr float SLOPE = 0.2f;

typedef __attribute__((ext_vector_type(8))) short short8;   // 8 bf16 (4 VGPRs)
typedef __attribute__((ext_vector_type(4))) float f32x4;    // MFMA C/D
typedef __hip_bfloat16 bf16;

// ---------------------------------------------------------------------------
__global__ void zero_k(float* __restrict__ p, int n) {
    int i = blockIdx.x * 256 + threadIdx.x;
    if (i < n) p[i] = 0.f;
}

// fp32 -> bf16 convert (4 elements/thread)
__global__ void conv_k(const float4* __restrict__ src, bf16* __restrict__ dst, int n4) {
    int i = blockIdx.x * 256 + threadIdx.x;
    if (i >= n4) return;
    float4 v = src[i];
    bf16* o = dst + (size_t)i * 4;
    o[0] = __float2bfloat16(v.x); o[1] = __float2bfloat16(v.y);
    o[2] = __float2bfloat16(v.z); o[3] = __float2bfloat16(v.w);
}

// W [768,768] row-major [k][n] fp32  ->  Wt [n][k] bf16 (transpose + convert)
__global__ __launch_bounds__(256) void wconv_k(const float* __restrict__ W,
                                               bf16* __restrict__ Wt) {
    __shared__ float tile[32][33];
    int bx = blockIdx.x * 32;   // n base
    int by = blockIdx.y * 32;   // k base
    int tx = threadIdx.x & 31, ty = threadIdx.x >> 5;   // ty 0..7
    #pragma unroll
    for (int r = 0; r < 32; r += 8)
        tile[ty + r][tx] = W[(size_t)(by + ty + r) * HD + bx + tx];
    __syncthreads();
    #pragma unroll
    for (int r = 0; r < 32; r += 8)
        Wt[(size_t)(bx + ty + r) * HD + by + tx] = __float2bfloat16(tile[tx][ty + r]);
}

// ---------------------------------------------------------------------------
// bf16 MFMA GEMM: C[M,768] = A[M,768] @ Bt[768,768]^T
// A, Bt bf16 row-major [row][k]. Tile 128x128, BK=32, 256 thr (4 waves),
// each wave 4x4 grid of 16x16x32 MFMA. global_load_lds width-16 staging (m97).
// BF16_OUT: write bf16 C (no bias). else: write fp32 C (+bias).
__device__ __forceinline__ void load16_lds(const void* g, void* l) {
    __builtin_amdgcn_global_load_lds(
        (const __attribute__((address_space(1))) unsigned int*)g,
        (__attribute__((address_space(3))) unsigned int*)l, 16, 0, 0);
}

template <bool BF16_OUT>
__global__ __launch_bounds__(256) void gemm_bf16_k(
    const bf16* __restrict__ A, const bf16* __restrict__ Bt,
    float* __restrict__ Cf, bf16* __restrict__ Cb, const float* __restrict__ bias)
{
    constexpr int K = HD;
    __shared__ __attribute__((aligned(16))) short As[128 * 32];
    __shared__ __attribute__((aligned(16))) short Bs[128 * 32];

    int tid  = threadIdx.x;
    int wave = tid >> 6, lane = tid & 63;
    int wy = wave >> 1, wx = wave & 1;          // wave quadrant (64x64)
    int m16 = lane & 15, quad = lane >> 4;      // MFMA fragment coords
    int bm = blockIdx.y * 128;
    int bn = blockIdx.x * 128;

    // staging positions: p = wave*128 + t*64 + lane -> chunk (row=p>>2, c=p&3)
    int p0 = wave * 128 + lane;                  // t=0
    int r0 = p0 >> 2, c0 = p0 & 3;
    int p1 = p0 + 64;                            // t=1
    int r1 = p1 >> 2, c1 = p1 & 3;

    const bf16* gA0 = A  + (size_t)(bm + r0) * K + c0 * 8;
    const bf16* gA1 = A  + (size_t)(bm + r1) * K + c1 * 8;
    const bf16* gB0 = Bt + (size_t)(bn + r0) * K + c0 * 8;
    const bf16* gB1 = Bt + (size_t)(bn + r1) * K + c1 * 8;

    f32x4 acc[4][4];
    #pragma unroll
    for (int i = 0; i < 4; i++)
        #pragma unroll
        for (int j = 0; j < 4; j++) acc[i][j] = (f32x4)0.f;

    const short8* Ac = (const short8*)As;
    const short8* Bc = (const short8*)Bs;

    for (int k0 = 0; k0 < K; k0 += 32) {
        load16_lds(gA0 + k0, &As[p0 * 8]);
        load16_lds(gA1 + k0, &As[p1 * 8]);
        load16_lds(gB0 + k0, &Bs[p0 * 8]);
        load16_lds(gB1 + k0, &Bs[p1 * 8]);
        __syncthreads();   // drains vmcnt(0): LDS tiles ready

        short8 a[4], b[4];
        #pragma unroll
        for (int i = 0; i < 4; i++)
            a[i] = Ac[(wy * 64 + i * 16 + m16) * 4 + quad];
        #pragma unroll
        for (int j = 0; j < 4; j++)
            b[j] = Bc[(wx * 64 + j * 16 + m16) * 4 + quad];
        #pragma unroll
        for (int i = 0; i < 4; i++)
            #pragma unroll
            for (int j = 0; j < 4; j++)
                acc[i][j] = __builtin_amdgcn_mfma_f32_16x16x32_bf16(a[i], b[j], acc[i][j], 0, 0, 0);
        __syncthreads();   // all ds_reads done before next staging overwrites
    }

    // epilogue: C/D layout col=lane&15, row=(lane>>4)*4+reg
    #pragma unroll
    for (int j = 0; j < 4; j++) {
        int col = bn + wx * 64 + j * 16 + m16;
        float badd = (!BF16_OUT && bias) ? bias[col] : 0.f;
        #pragma unroll
        for (int i = 0; i < 4; i++) {
            int row0 = bm + wy * 64 + i * 16 + quad * 4;
            #pragma unroll
            for (int r = 0; r < 4; r++) {
                if (BF16_OUT)
                    Cb[(size_t)(row0 + r) * HD + col] = __float2bfloat16(acc[i][j][r]);
                else
                    Cf[(size_t)(row0 + r) * HD + col] = acc[i][j][r] + badd;
            }
        }
    }
}

// ---------------------------------------------------------------------------
// per-node attention logits: asrc[n,h] = dot(xw[n,h,:], att_src[h,:])
__global__ __launch_bounds__(256) void alpha_k(
    const bf16* __restrict__ xw,
    const float* __restrict__ asl, const float* __restrict__ adl,
    float* __restrict__ asrc, float* __restrict__ adst)
{
    int n = blockIdx.x, t = threadIdx.x;
    int head = t >> 6, lane = t & 63;
    const bf16* row = xw + (size_t)n * HD + head * DD;
    const float* a1 = asl + head * DD;
    const float* a2 = adl + head * DD;
    float s1 = 0.f, s2 = 0.f;
    #pragma unroll
    for (int j = 0; j < 3; j++) {      // DD = 192 = 3*64
        int d = lane + 64 * j;
        float v = __bfloat162float(row[d]);
        s1 += v * a1[d]; s2 += v * a2[d];
    }
    #pragma unroll
    for (int off = 32; off > 0; off >>= 1) {
        s1 += __shfl_down(s1, off, 64);
        s2 += __shfl_down(s2, off, 64);
    }
    if (lane == 0) {
        asrc[(size_t)n * HH + head] = s1;
        adst[(size_t)n * HH + head] = s2;
    }
}

// ---------------------------------------------------------------------------
// CSR build over dst
__global__ void hist_k(const int* __restrict__ ei, int* __restrict__ deg) {
    int e = blockIdx.x * 256 + threadIdx.x;   // grid == E2 exactly
    int dst = (e < EE) ? ei[EE + e] : (e - EE);
    atomicAdd(&deg[dst], 1);
}

__global__ void scan1_k(const int* __restrict__ deg, int* __restrict__ incl,
                        int* __restrict__ blocksum) {
    __shared__ int s[256];
    int t = threadIdx.x, n = blockIdx.x * 256 + t;
    int v = deg[n];
    s[t] = v;
    for (int off = 1; off < 256; off <<= 1) {
        __syncthreads();
        int tmp = (t >= off) ? s[t - off] : 0;
        __syncthreads();
        s[t] += tmp;
    }
    incl[n] = s[t];
    if (t == 255) blocksum[blockIdx.x] = s[255];
}

__global__ void scan2_k(const int* __restrict__ blocksum, int* __restrict__ blockoff) {
    __shared__ int s[256];
    int t = threadIdx.x;
    int v = blocksum[t];
    s[t] = v;
    for (int off = 1; off < 256; off <<= 1) {
        __syncthreads();
        int tmp = (t >= off) ? s[t - off] : 0;
        __syncthreads();
        s[t] += tmp;
    }
    blockoff[t] = s[t] - v;   // exclusive
}

__global__ void scan3_k(const int* __restrict__ deg, const int* __restrict__ blockoff,
                        int* __restrict__ incl_cursor, int* __restrict__ rowstart) {
    int t = threadIdx.x, n = blockIdx.x * 256 + t;
    int rs = blockoff[blockIdx.x] + incl_cursor[n] - deg[n];
    rowstart[n] = rs;
    incl_cursor[n] = rs;       // becomes the fill cursor
    if (n == 0) rowstart[NN] = E2;
}

__global__ void fill_k(const int* __restrict__ ei, int* __restrict__ cursor,
                       int* __restrict__ csr_src, int* __restrict__ csr_eid) {
    int e = blockIdx.x * 256 + threadIdx.x;
    int src = (e < EE) ? ei[e] : (e - EE);
    int dst = (e < EE) ? ei[EE + e] : (e - EE);
    int pos = atomicAdd(&cursor[dst], 1);
    csr_src[pos] = src;
    csr_eid[pos] = e;
}

// ---------------------------------------------------------------------------
// edge kernel: ex[e,h] = exp(leaky_relu(asrc[src,h]+adst[dst,h]))
// (no max-shift: logits are O(1), softmax is shift-invariant)
__global__ void edge_k(const int* __restrict__ ei,
                       const float4* __restrict__ asrc, const float4* __restrict__ adst,
                       float4* __restrict__ ex, float* __restrict__ denom) {
    int e = blockIdx.x * 256 + threadIdx.x;
    int src = (e < EE) ? ei[e] : (e - EE);
    int dst = (e < EE) ? ei[EE + e] : (e - EE);
    float4 a = asrc[src], b = adst[dst];
    float4 v;
    float t0 = a.x + b.x; t0 = (t0 > 0.f) ? t0 : SLOPE * t0; v.x = expf(t0);
    float t1 = a.y + b.y; t1 = (t1 > 0.f) ? t1 : SLOPE * t1; v.y = expf(t1);
    float t2 = a.z + b.z; t2 = (t2 > 0.f) ? t2 : SLOPE * t2; v.z = expf(t2);
    float t3 = a.w + b.w; t3 = (t3 > 0.f) ? t3 : SLOPE * t3; v.w = expf(t3);
    ex[e] = v;
    atomicAdd(&denom[(size_t)dst * 4 + 0], v.x);
    atomicAdd(&denom[(size_t)dst * 4 + 1], v.y);
    atomicAdd(&denom[(size_t)dst * 4 + 2], v.z);
    atomicAdd(&denom[(size_t)dst * 4 + 3], v.w);
}

// ---------------------------------------------------------------------------
__device__ __forceinline__ float blk_sum(float v, float* sm) {
    #pragma unroll
    for (int off = 32; off > 0; off >>= 1) v += __shfl_down(v, off, 64);
    __syncthreads();                       // protect sm reuse across calls
    if ((threadIdx.x & 63) == 0) sm[threadIdx.x >> 6] = v;
    __syncthreads();
    return sm[0] + sm[1] + sm[2] + sm[3];
}

// aggregation + bias + LayerNorm + ReLU + residual; all bf16 streams,
// fp32 accumulation in-register.
__global__ __launch_bounds__(256) void agg_k(
    const bf16* __restrict__ xw, const float4* __restrict__ ex,
    const float4* __restrict__ denom, const int* __restrict__ rowstart,
    const int* __restrict__ csr_src, const int* __restrict__ csr_eid,
    const float* __restrict__ bias_l, const float* __restrict__ gamma_l,
    const float* __restrict__ beta_l, const bf16* __restrict__ h_in,
    bf16* __restrict__ h_out)
{
    int i = blockIdx.x, t = threadIdx.x;
    __shared__ int   s_src[64];
    __shared__ float s_w[64][4];
    __shared__ float s_red[4];

    int r0 = rowstart[i], r1 = rowstart[i + 1];
    float4 dn = denom[i];
    float inv0 = 1.f / dn.x, inv1 = 1.f / dn.y, inv2 = 1.f / dn.z, inv3 = 1.f / dn.w;

    int c0 = t, c1 = t + 256, c2 = t + 512;
    int h0 = c0 / DD, h1 = c1 / DD, h2 = c2 / DD;
    float a0 = 0.f, a1 = 0.f, a2 = 0.f;

    for (int base = r0; base < r1; base += 64) {
        int cnt = min(64, r1 - base);
        if (t < cnt) {
            s_src[t] = csr_src[base + t];
            float4 w = ex[csr_eid[base + t]];
            s_w[t][0] = w.x * inv0; s_w[t][1] = w.y * inv1;
            s_w[t][2] = w.z * inv2; s_w[t][3] = w.w * inv3;
        }
        __syncthreads();
        for (int e = 0; e < cnt; e++) {
            const bf16* row = xw + (size_t)s_src[e] * HD;
            a0 += s_w[e][h0] * __bfloat162float(row[c0]);
            a1 += s_w[e][h1] * __bfloat162float(row[c1]);
            a2 += s_w[e][h2] * __bfloat162float(row[c2]);
        }
        __syncthreads();
    }

    float v0 = a0 + bias_l[c0], v1 = a1 + bias_l[c1], v2 = a2 + bias_l[c2];
    float mean = blk_sum(v0 + v1 + v2, s_red) * (1.f / (float)HD);
    float d0 = v0 - mean, d1 = v1 - mean, d2 = v2 - mean;
    float var = blk_sum(d0 * d0 + d1 * d1 + d2 * d2, s_red) * (1.f / (float)HD);
    float rs = rsqrtf(var + EPS);

    const bf16* hrow = h_in + (size_t)i * HD;
    bf16* orow = h_out + (size_t)i * HD;
    float o0 = fmaxf(d0 * rs * gamma_l[c0] + beta_l[c0], 0.f) + __bfloat162float(hrow[c0]);
    float o1 = fmaxf(d1 * rs * gamma_l[c1] + beta_l[c1], 0.f) + __bfloat162float(hrow[c1]);
    float o2 = fmaxf(d2 * rs * gamma_l[c2] + beta_l[c2], 0.f) + __bfloat162float(hrow[c2]);
    orow[c0] = __float2bfloat16(o0); orow[c1] = __float2bfloat16(o1);
    orow[c2] = __float2bfloat16(o2);
}

// ---------------------------------------------------------------------------
// global mean pool per graph -> bf16 hg (input to final MFMA GEMM)
__global__ __launch_bounds__(256) void pool_k(
    const bf16* __restrict__ h, const int* __restrict__ bv,
    bf16* __restrict__ hg)
{
    int g = blockIdx.x, t = threadIdx.x;
    int lo = 0, hi = NN;
    while (lo < hi) { int mid = (lo + hi) >> 1; if (bv[mid] < g) lo = mid + 1; else hi = mid; }
    int start = lo;
    hi = NN;
    while (lo < hi) { int mid = (lo + hi) >> 1; if (bv[mid] < g + 1) lo = mid + 1; else hi = mid; }
    int end = lo;
    float a0 = 0.f, a1 = 0.f, a2 = 0.f;
    for (int n = start; n < end; n++) {
        const bf16* row = h + (size_t)n * HD;
        a0 += __bfloat162float(row[t]);
        a1 += __bfloat162float(row[t + 256]);
        a2 += __bfloat162float(row[t + 512]);
    }
    float sc = 1.f / fmaxf((float)(end - start), 1.f);
    bf16* o = hg + (size_t)g * HD;
    o[t]       = __float2bfloat16(a0 * sc);
    o[t + 256] = __float2bfloat16(a1 * sc);
    o[t + 512] = __float2bfloat16(a2 * sc);
}

// ---------------------------------------------------------------------------
extern "C" void kernel_launch(void* const* d_in, const int* in_sizes, int n_in,
                              void* d_out, int out_size, void* d_ws, size_t ws_size,
                              hipStream_t stream)
{
    (void)in_sizes; (void)n_in; (void)out_size; (void)ws_size;
    const float* x       = (const float*)d_in[0];
    const int*   ei      = (const int*)d_in[1];
    const int*   bv      = (const int*)d_in[2];
    const float* W       = (const float*)d_in[3];
    const float* att_src = (const float*)d_in[4];
    const float* att_dst = (const float*)d_in[5];
    const float* bias    = (const float*)d_in[6];
    const float* gamma   = (const float*)d_in[7];
    const float* beta    = (const float*)d_in[8];
    const float* out_w   = (const float*)d_in[9];
    const float* out_b   = (const float*)d_in[10];
    float* out = (float*)d_out;

    char* p = (char*)d_ws;
    size_t off = 0;
    auto take = [&](size_t bytes) -> char* {
        char* r = p + off;
        off = (off + bytes + 255) & ~(size_t)255;
        return r;
    };
    bf16* xw        = (bf16*)take((size_t)NN * HD * 2);   // bf16 projected feats
    bf16* hbf0      = (bf16*)take((size_t)NN * HD * 2);   // h ping
    bf16* hbf1      = (bf16*)take((size_t)NN * HD * 2);   // h pong
    bf16* Wt        = (bf16*)take((size_t)HD * HD * 2);
    bf16* OWt       = (bf16*)take((size_t)HD * HD * 2);
    float* asrc     = (float*)take((size_t)NN * HH * 4);
    float* adst     = (float*)take((size_t)NN * HH * 4);
    float* ex       = (float*)take((size_t)E2 * HH * 4);
    float* denom    = (float*)take((size_t)NN * HH * 4);
    int*   deg      = (int*)take((size_t)NN * 4);
    int*   rowstart = (int*)take((size_t)(NN + 1) * 4);
    int*   cursor   = (int*)take((size_t)NN * 4);
    int*   blocksum = (int*)take(256 * 4);
    int*   blockoff = (int*)take(256 * 4);
    int*   csr_src  = (int*)take((size_t)E2 * 4);
    int*   csr_eid  = (int*)take((size_t)E2 * 4);
    bf16*  hg       = (bf16*)take((size_t)BB * HD * 2);

    const int EB = E2 / 256;   // 1280, exact

    // ---- CSR build (topology only, once) ----
    zero_k<<<NN / 256, 256, 0, stream>>>((float*)deg, NN);
    hist_k<<<EB, 256, 0, stream>>>(ei, deg);
    scan1_k<<<NN / 256, 256, 0, stream>>>(deg, cursor, blocksum);
    scan2_k<<<1, 256, 0, stream>>>(blocksum, blockoff);
    scan3_k<<<NN / 256, 256, 0, stream>>>(deg, blockoff, cursor, rowstart);
    fill_k<<<EB, 256, 0, stream>>>(ei, cursor, csr_src, csr_eid);

    // ---- bf16 conversions: x -> hbf0 (layer-0 A + residual) ----
    conv_k<<<(NN * HD / 4 + 255) / 256, 256, 0, stream>>>((const float4*)x, hbf0, NN * HD / 4);

    // ---- layers (ping-pong h buffers) ----
    bf16* hin = hbf0;
    bf16* hout = hbf1;
    for (int l = 0; l < LL; l++) {
        wconv_k<<<dim3(HD / 32, HD / 32), 256, 0, stream>>>(W + (size_t)l * HD * HD, Wt);
        gemm_bf16_k<true><<<dim3(HD / 128, NN / 128), 256, 0, stream>>>(
            hin, Wt, nullptr, xw, nullptr);
        alpha_k<<<NN, 256, 0, stream>>>(xw, att_src + (size_t)l * HH * DD,
                                        att_dst + (size_t)l * HH * DD, asrc, adst);
        zero_k<<<NN * HH / 256, 256, 0, stream>>>(denom, NN * HH);
        edge_k<<<EB, 256, 0, stream>>>(ei, (const float4*)asrc, (const float4*)adst,
                                       (float4*)ex, denom);
        agg_k<<<NN, 256, 0, stream>>>(xw, (const float4*)ex, (const float4*)denom,
                                      rowstart, csr_src, csr_eid,
                                      bias + (size_t)l * HD, gamma + (size_t)l * HD,
                                      beta + (size_t)l * HD, hin, hout);
        bf16* tmp = hin; hin = hout; hout = tmp;
    }

    // ---- pooling + output projection (bf16 MFMA, fp32 out) ----
    pool_k<<<BB, 256, 0, stream>>>(hin, bv, hg);
    wconv_k<<<dim3(HD / 32, HD / 32), 256, 0, stream>>>(out_w, OWt);
    gemm_bf16_k<false><<<dim3(HD / 128, BB / 128), 256, 0, stream>>>(
        hg, OWt, out, nullptr, out_b);
}

// Round 5
// 1087.315 us; speedup vs baseline: 2.6144x; 1.0326x over previous
//
#include <hip/hip_runtime.h>
#include <hip/hip_bf16.h>

// Problem constants (match reference)
constexpr int NN  = 65536;           // nodes
constexpr int EE  = 262144;          // edges before self loops
constexpr int E2  = EE + NN;         // 327680 edges with self loops
constexpr int BB  = 2048;            // graphs
constexpr int HH  = 4;               // heads
constexpr int DD  = 192;             // per-head dim
constexpr int HD  = 768;             // hidden
constexpr int LL  = 2;               // layers
constexpr float EPS = 1e-5f;
constexpr float SLOPE = 0.2f;

typedef __attribute__((ext_vector_type(8))) short short8;   // 8 bf16 (4 VGPRs)
typedef __attribute__((ext_vector_type(4))) float f32x4;    // MFMA C/D
typedef __hip_bfloat16 bf16;

// ---------------------------------------------------------------------------
__global__ void zero_k(float* __restrict__ p, int n) {
    int i = blockIdx.x * 256 + threadIdx.x;
    if (i < n) p[i] = 0.f;
}

// fp32 -> bf16 convert (4 elements/thread)
__global__ void conv_k(const float4* __restrict__ src, bf16* __restrict__ dst, int n4) {
    int i = blockIdx.x * 256 + threadIdx.x;
    if (i >= n4) return;
    float4 v = src[i];
    bf16* o = dst + (size_t)i * 4;
    o[0] = __float2bfloat16(v.x); o[1] = __float2bfloat16(v.y);
    o[2] = __float2bfloat16(v.z); o[3] = __float2bfloat16(v.w);
}

// All 3 weight matrices (W0, W1, out_w): [k][n] fp32 -> [n][k] bf16, one dispatch
__global__ __launch_bounds__(256) void wconv3_k(const float* __restrict__ W,
                                                const float* __restrict__ OW,
                                                bf16* __restrict__ Wt3) {
    __shared__ float tile[32][33];
    const float* src = (blockIdx.z < 2) ? (W + (size_t)blockIdx.z * HD * HD) : OW;
    bf16* dst = Wt3 + (size_t)blockIdx.z * HD * HD;
    int bx = blockIdx.x * 32;   // n base
    int by = blockIdx.y * 32;   // k base
    int tx = threadIdx.x & 31, ty = threadIdx.x >> 5;   // ty 0..7
    #pragma unroll
    for (int r = 0; r < 32; r += 8)
        tile[ty + r][tx] = src[(size_t)(by + ty + r) * HD + bx + tx];
    __syncthreads();
    #pragma unroll
    for (int r = 0; r < 32; r += 8)
        dst[(size_t)(bx + ty + r) * HD + by + tx] = __float2bfloat16(tile[tx][ty + r]);
}

// ---------------------------------------------------------------------------
// bf16 MFMA GEMM: C[M,768] = A[M,768] @ Bt[768,768]^T
// A, Bt bf16 row-major [row][k]. Tile 128x128, BK=32, 256 thr (4 waves),
// each wave 4x4 grid of 16x16x32 MFMA. global_load_lds width-16 staging (m97).
// SWIZ: XCD-aware flat-grid swizzle for the 512x6 block grid — each XCD owns
// 64 row-strips walked as 8-row x 6-col super-tiles (A 1.6MB + B 1.2MB < L2).
__device__ __forceinline__ void load16_lds(const void* g, void* l) {
    __builtin_amdgcn_global_load_lds(
        (const __attribute__((address_space(1))) unsigned int*)g,
        (__attribute__((address_space(3))) unsigned int*)l, 16, 0, 0);
}

template <bool BF16_OUT, bool SWIZ>
__global__ __launch_bounds__(256) void gemm_bf16_k(
    const bf16* __restrict__ A, const bf16* __restrict__ Bt,
    float* __restrict__ Cf, bf16* __restrict__ Cb, const float* __restrict__ bias)
{
    constexpr int K = HD;
    __shared__ __attribute__((aligned(16))) short As[128 * 32];
    __shared__ __attribute__((aligned(16))) short Bs[128 * 32];

    int bx, by;
    if (SWIZ) {
        int gid = blockIdx.x;            // flat 3072 = 8 XCD * 8 sg * 48
        int xcd = gid & 7, lid = gid >> 3;   // lid 0..383
        int sg = lid / 48, sl = lid - sg * 48;
        by = (xcd << 6) + (sg << 3) + (sl & 7);   // row strip 0..511
        bx = sl >> 3;                              // col 0..5
    } else {
        bx = blockIdx.x; by = blockIdx.y;
    }

    int tid  = threadIdx.x;
    int wave = tid >> 6, lane = tid & 63;
    int wy = wave >> 1, wx = wave & 1;          // wave quadrant (64x64)
    int m16 = lane & 15, quad = lane >> 4;      // MFMA fragment coords
    int bm = by * 128;
    int bn = bx * 128;

    // staging positions: p = wave*128 + t*64 + lane -> chunk (row=p>>2, c=p&3)
    int p0 = wave * 128 + lane;                  // t=0
    int r0 = p0 >> 2, c0 = p0 & 3;
    int p1 = p0 + 64;                            // t=1
    int r1 = p1 >> 2, c1 = p1 & 3;

    const bf16* gA0 = A  + (size_t)(bm + r0) * K + c0 * 8;
    const bf16* gA1 = A  + (size_t)(bm + r1) * K + c1 * 8;
    const bf16* gB0 = Bt + (size_t)(bn + r0) * K + c0 * 8;
    const bf16* gB1 = Bt + (size_t)(bn + r1) * K + c1 * 8;

    f32x4 acc[4][4];
    #pragma unroll
    for (int i = 0; i < 4; i++)
        #pragma unroll
        for (int j = 0; j < 4; j++) acc[i][j] = (f32x4)0.f;

    const short8* Ac = (const short8*)As;
    const short8* Bc = (const short8*)Bs;

    for (int k0 = 0; k0 < K; k0 += 32) {
        load16_lds(gA0 + k0, &As[p0 * 8]);
        load16_lds(gA1 + k0, &As[p1 * 8]);
        load16_lds(gB0 + k0, &Bs[p0 * 8]);
        load16_lds(gB1 + k0, &Bs[p1 * 8]);
        __syncthreads();   // drains vmcnt(0): LDS tiles ready

        short8 a[4], b[4];
        #pragma unroll
        for (int i = 0; i < 4; i++)
            a[i] = Ac[(wy * 64 + i * 16 + m16) * 4 + quad];
        #pragma unroll
        for (int j = 0; j < 4; j++)
            b[j] = Bc[(wx * 64 + j * 16 + m16) * 4 + quad];
        #pragma unroll
        for (int i = 0; i < 4; i++)
            #pragma unroll
            for (int j = 0; j < 4; j++)
                acc[i][j] = __builtin_amdgcn_mfma_f32_16x16x32_bf16(a[i], b[j], acc[i][j], 0, 0, 0);
        __syncthreads();   // all ds_reads done before next staging overwrites
    }

    // epilogue: C/D layout col=lane&15, row=(lane>>4)*4+reg
    #pragma unroll
    for (int j = 0; j < 4; j++) {
        int col = bn + wx * 64 + j * 16 + m16;
        float badd = (!BF16_OUT && bias) ? bias[col] : 0.f;
        #pragma unroll
        for (int i = 0; i < 4; i++) {
            int row0 = bm + wy * 64 + i * 16 + quad * 4;
            #pragma unroll
            for (int r = 0; r < 4; r++) {
                if (BF16_OUT)
                    Cb[(size_t)(row0 + r) * HD + col] = __float2bfloat16(acc[i][j][r]);
                else
                    Cf[(size_t)(row0 + r) * HD + col] = acc[i][j][r] + badd;
            }
        }
    }
}

// ---------------------------------------------------------------------------
// per-node attention logits: asrc[n,h] = dot(xw[n,h,:], att_src[h,:]);
// also zeroes denom (runs strictly before edge_k's atomics).
__global__ __launch_bounds__(256) void alpha_k(
    const bf16* __restrict__ xw,
    const float* __restrict__ asl, const float* __restrict__ adl,
    float* __restrict__ asrc, float* __restrict__ adst, float* __restrict__ denom)
{
    int n = blockIdx.x, t = threadIdx.x;
    if (t < 4) denom[(size_t)n * 4 + t] = 0.f;
    int head = t >> 6, lane = t & 63;
    const bf16* row = xw + (size_t)n * HD + head * DD;
    const float* a1 = asl + head * DD;
    const float* a2 = adl + head * DD;
    float s1 = 0.f, s2 = 0.f;
    #pragma unroll
    for (int j = 0; j < 3; j++) {      // DD = 192 = 3*64
        int d = lane + 64 * j;
        float v = __bfloat162float(row[d]);
        s1 += v * a1[d]; s2 += v * a2[d];
    }
    #pragma unroll
    for (int off = 32; off > 0; off >>= 1) {
        s1 += __shfl_down(s1, off, 64);
        s2 += __shfl_down(s2, off, 64);
    }
    if (lane == 0) {
        asrc[(size_t)n * HH + head] = s1;
        adst[(size_t)n * HH + head] = s2;
    }
}

// ---------------------------------------------------------------------------
// CSR build over dst
__global__ void hist_k(const int* __restrict__ ei, int* __restrict__ deg) {
    int e = blockIdx.x * 256 + threadIdx.x;   // grid == E2 exactly
    int dst = (e < EE) ? ei[EE + e] : (e - EE);
    atomicAdd(&deg[dst], 1);
}

__global__ void scan1_k(const int* __restrict__ deg, int* __restrict__ incl,
                        int* __restrict__ blocksum) {
    __shared__ int s[256];
    int t = threadIdx.x, n = blockIdx.x * 256 + t;
    int v = deg[n];
    s[t] = v;
    for (int off = 1; off < 256; off <<= 1) {
        __syncthreads();
        int tmp = (t >= off) ? s[t - off] : 0;
        __syncthreads();
        s[t] += tmp;
    }
    incl[n] = s[t];
    if (t == 255) blocksum[blockIdx.x] = s[255];
}

__global__ void scan2_k(const int* __restrict__ blocksum, int* __restrict__ blockoff) {
    __shared__ int s[256];
    int t = threadIdx.x;
    int v = blocksum[t];
    s[t] = v;
    for (int off = 1; off < 256; off <<= 1) {
        __syncthreads();
        int tmp = (t >= off) ? s[t - off] : 0;
        __syncthreads();
        s[t] += tmp;
    }
    blockoff[t] = s[t] - v;   // exclusive
}

__global__ void scan3_k(const int* __restrict__ deg, const int* __restrict__ blockoff,
                        int* __restrict__ incl_cursor, int* __restrict__ rowstart) {
    int t = threadIdx.x, n = blockIdx.x * 256 + t;
    int rs = blockoff[blockIdx.x] + incl_cursor[n] - deg[n];
    rowstart[n] = rs;
    incl_cursor[n] = rs;       // becomes the fill cursor
    if (n == 0) rowstart[NN] = E2;
}

__global__ void fill_k(const int* __restrict__ ei, int* __restrict__ cursor,
                       int* __restrict__ csr_src, int* __restrict__ inv_eid) {
    int e = blockIdx.x * 256 + threadIdx.x;
    int src = (e < EE) ? ei[e] : (e - EE);
    int dst = (e < EE) ? ei[EE + e] : (e - EE);
    int pos = atomicAdd(&cursor[dst], 1);
    csr_src[pos] = src;
    inv_eid[e] = pos;          // edge id -> CSR slot (for CSR-ordered ex)
}

// ---------------------------------------------------------------------------
// edge kernel: ex_csr[inv[e],h] = exp(leaky_relu(asrc[src,h]+adst[dst,h]))
// (no max-shift: logits are O(1), softmax is shift-invariant)
__global__ void edge_k(const int* __restrict__ ei, const int* __restrict__ inv_eid,
                       const float4* __restrict__ asrc, const float4* __restrict__ adst,
                       float4* __restrict__ ex_csr, float* __restrict__ denom) {
    int e = blockIdx.x * 256 + threadIdx.x;
    int src = (e < EE) ? ei[e] : (e - EE);
    int dst = (e < EE) ? ei[EE + e] : (e - EE);
    float4 a = asrc[src], b = adst[dst];
    float4 v;
    float t0 = a.x + b.x; t0 = (t0 > 0.f) ? t0 : SLOPE * t0; v.x = expf(t0);
    float t1 = a.y + b.y; t1 = (t1 > 0.f) ? t1 : SLOPE * t1; v.y = expf(t1);
    float t2 = a.z + b.z; t2 = (t2 > 0.f) ? t2 : SLOPE * t2; v.z = expf(t2);
    float t3 = a.w + b.w; t3 = (t3 > 0.f) ? t3 : SLOPE * t3; v.w = expf(t3);
    ex_csr[inv_eid[e]] = v;
    atomicAdd(&denom[(size_t)dst * 4 + 0], v.x);
    atomicAdd(&denom[(size_t)dst * 4 + 1], v.y);
    atomicAdd(&denom[(size_t)dst * 4 + 2], v.z);
    atomicAdd(&denom[(size_t)dst * 4 + 3], v.w);
}

// ---------------------------------------------------------------------------
// block reduce over 3 waves (192 threads)
__device__ __forceinline__ float blk_sum3(float v, float* sm) {
    #pragma unroll
    for (int off = 32; off > 0; off >>= 1) v += __shfl_down(v, off, 64);
    __syncthreads();                       // protect sm reuse across calls
    if ((threadIdx.x & 63) == 0) sm[threadIdx.x >> 6] = v;
    __syncthreads();
    return sm[0] + sm[1] + sm[2];
}

__device__ __forceinline__ float bflo(unsigned u) { return __uint_as_float(u << 16); }
__device__ __forceinline__ float bfhi(unsigned u) { return __uint_as_float(u & 0xffff0000u); }

// aggregation + bias + LayerNorm + ReLU + residual.
// 192 threads/block, 4 contiguous channels per thread (uint2 = 4 bf16 / edge),
// SGPR row base via readfirstlane, CSR-ordered coalesced weights.
__global__ __launch_bounds__(192) void agg_k(
    const bf16* __restrict__ xw, const float4* __restrict__ ex_csr,
    const float4* __restrict__ denom, const int* __restrict__ rowstart,
    const int* __restrict__ csr_src,
    const float* __restrict__ bias_l, const float* __restrict__ gamma_l,
    const float* __restrict__ beta_l, const bf16* __restrict__ h_in,
    bf16* __restrict__ h_out)
{
    int i = blockIdx.x, t = threadIdx.x;        // t in [0,192)
    __shared__ int   s_src[64];
    __shared__ float s_w[64][4];
    __shared__ float s_red[3];

    int r0 = rowstart[i], r1 = rowstart[i + 1];
    float4 dn = denom[i];
    float inv0 = 1.f / dn.x, inv1 = 1.f / dn.y, inv2 = 1.f / dn.z, inv3 = 1.f / dn.w;

    int c = t * 4;                 // channel base; 192*4 = 768
    int hidx = t / 48;             // head (192 channels per head / 4 = 48 threads)
    float a0 = 0.f, a1 = 0.f, a2 = 0.f, a3 = 0.f;

    for (int base = r0; base < r1; base += 64) {
        int cnt = min(64, r1 - base);
        if (t < cnt) {
            s_src[t] = csr_src[base + t];
            float4 w = ex_csr[base + t];           // coalesced CSR-ordered
            s_w[t][0] = w.x * inv0; s_w[t][1] = w.y * inv1;
            s_w[t][2] = w.z * inv2; s_w[t][3] = w.w * inv3;
        }
        __syncthreads();
        for (int e = 0; e < cnt; e++) {
            int src = __builtin_amdgcn_readfirstlane(s_src[e]);   // SGPR base
            float wv = s_w[e][hidx];
            uint2 u = *(const uint2*)(xw + (size_t)src * HD + c);
            a0 += wv * bflo(u.x); a1 += wv * bfhi(u.x);
            a2 += wv * bflo(u.y); a3 += wv * bfhi(u.y);
        }
        __syncthreads();
    }

    float4 bv = *(const float4*)&bias_l[c];
    float v0 = a0 + bv.x, v1 = a1 + bv.y, v2 = a2 + bv.z, v3 = a3 + bv.w;
    float mean = blk_sum3(v0 + v1 + v2 + v3, s_red) * (1.f / (float)HD);
    float d0 = v0 - mean, d1 = v1 - mean, d2 = v2 - mean, d3 = v3 - mean;
    float var = blk_sum3(d0 * d0 + d1 * d1 + d2 * d2 + d3 * d3, s_red) * (1.f / (float)HD);
    float rs = rsqrtf(var + EPS);

    float4 gv = *(const float4*)&gamma_l[c];
    float4 btv = *(const float4*)&beta_l[c];
    uint2 hr = *(const uint2*)(h_in + (size_t)i * HD + c);
    float o0 = fmaxf(d0 * rs * gv.x + btv.x, 0.f) + bflo(hr.x);
    float o1 = fmaxf(d1 * rs * gv.y + btv.y, 0.f) + bfhi(hr.x);
    float o2 = fmaxf(d2 * rs * gv.z + btv.z, 0.f) + bflo(hr.y);
    float o3 = fmaxf(d3 * rs * gv.w + btv.w, 0.f) + bfhi(hr.y);

    bf16 pk[4];
    pk[0] = __float2bfloat16(o0); pk[1] = __float2bfloat16(o1);
    pk[2] = __float2bfloat16(o2); pk[3] = __float2bfloat16(o3);
    *(uint2*)(h_out + (size_t)i * HD + c) = *(const uint2*)pk;
}

// ---------------------------------------------------------------------------
// global mean pool per graph -> bf16 hg (input to final MFMA GEMM)
__global__ __launch_bounds__(256) void pool_k(
    const bf16* __restrict__ h, const int* __restrict__ bv,
    bf16* __restrict__ hg)
{
    int g = blockIdx.x, t = threadIdx.x;
    int lo = 0, hi = NN;
    while (lo < hi) { int mid = (lo + hi) >> 1; if (bv[mid] < g) lo = mid + 1; else hi = mid; }
    int start = lo;
    hi = NN;
    while (lo < hi) { int mid = (lo + hi) >> 1; if (bv[mid] < g + 1) lo = mid + 1; else hi = mid; }
    int end = lo;
    float a0 = 0.f, a1 = 0.f, a2 = 0.f;
    for (int n = start; n < end; n++) {
        const bf16* row = h + (size_t)n * HD;
        a0 += __bfloat162float(row[t]);
        a1 += __bfloat162float(row[t + 256]);
        a2 += __bfloat162float(row[t + 512]);
    }
    float sc = 1.f / fmaxf((float)(end - start), 1.f);
    bf16* o = hg + (size_t)g * HD;
    o[t]       = __float2bfloat16(a0 * sc);
    o[t + 256] = __float2bfloat16(a1 * sc);
    o[t + 512] = __float2bfloat16(a2 * sc);
}

// ---------------------------------------------------------------------------
extern "C" void kernel_launch(void* const* d_in, const int* in_sizes, int n_in,
                              void* d_out, int out_size, void* d_ws, size_t ws_size,
                              hipStream_t stream)
{
    (void)in_sizes; (void)n_in; (void)out_size; (void)ws_size;
    const float* x       = (const float*)d_in[0];
    const int*   ei      = (const int*)d_in[1];
    const int*   bv      = (const int*)d_in[2];
    const float* W       = (const float*)d_in[3];
    const float* att_src = (const float*)d_in[4];
    const float* att_dst = (const float*)d_in[5];
    const float* bias    = (const float*)d_in[6];
    const float* gamma   = (const float*)d_in[7];
    const float* beta    = (const float*)d_in[8];
    const float* out_w   = (const float*)d_in[9];
    const float* out_b   = (const float*)d_in[10];
    float* out = (float*)d_out;

    char* p = (char*)d_ws;
    size_t off = 0;
    auto take = [&](size_t bytes) -> char* {
        char* r = p + off;
        off = (off + bytes + 255) & ~(size_t)255;
        return r;
    };
    bf16* xw        = (bf16*)take((size_t)NN * HD * 2);   // bf16 projected feats
    bf16* hbf0      = (bf16*)take((size_t)NN * HD * 2);   // h ping
    bf16* hbf1      = (bf16*)take((size_t)NN * HD * 2);   // h pong
    bf16* Wt3       = (bf16*)take((size_t)3 * HD * HD * 2); // W0,W1,out_w bf16^T
    float* asrc     = (float*)take((size_t)NN * HH * 4);
    float* adst     = (float*)take((size_t)NN * HH * 4);
    float* ex       = (float*)take((size_t)E2 * HH * 4);  // CSR-ordered
    float* denom    = (float*)take((size_t)NN * HH * 4);
    int*   deg      = (int*)take((size_t)NN * 4);
    int*   rowstart = (int*)take((size_t)(NN + 1) * 4);
    int*   cursor   = (int*)take((size_t)NN * 4);
    int*   blocksum = (int*)take(256 * 4);
    int*   blockoff = (int*)take(256 * 4);
    int*   csr_src  = (int*)take((size_t)E2 * 4);
    int*   inv_eid  = (int*)take((size_t)E2 * 4);
    bf16*  hg       = (bf16*)take((size_t)BB * HD * 2);

    const int EB = E2 / 256;   // 1280, exact

    // ---- CSR build (topology only, once) ----
    zero_k<<<NN / 256, 256, 0, stream>>>((float*)deg, NN);
    hist_k<<<EB, 256, 0, stream>>>(ei, deg);
    scan1_k<<<NN / 256, 256, 0, stream>>>(deg, cursor, blocksum);
    scan2_k<<<1, 256, 0, stream>>>(blocksum, blockoff);
    scan3_k<<<NN / 256, 256, 0, stream>>>(deg, blockoff, cursor, rowstart);
    fill_k<<<EB, 256, 0, stream>>>(ei, cursor, csr_src, inv_eid);

    // ---- bf16 conversions ----
    conv_k<<<(NN * HD / 4 + 255) / 256, 256, 0, stream>>>((const float4*)x, hbf0, NN * HD / 4);
    wconv3_k<<<dim3(HD / 32, HD / 32, 3), 256, 0, stream>>>(W, out_w, Wt3);

    // ---- layers (ping-pong h buffers) ----
    bf16* hin = hbf0;
    bf16* hout = hbf1;
    for (int l = 0; l < LL; l++) {
        gemm_bf16_k<true, true><<<3072, 256, 0, stream>>>(
            hin, Wt3 + (size_t)l * HD * HD, nullptr, xw, nullptr);
        alpha_k<<<NN, 256, 0, stream>>>(xw, att_src + (size_t)l * HH * DD,
                                        att_dst + (size_t)l * HH * DD, asrc, adst, denom);
        edge_k<<<EB, 256, 0, stream>>>(ei, inv_eid, (const float4*)asrc,
                                       (const float4*)adst, (float4*)ex, denom);
        agg_k<<<NN, 192, 0, stream>>>(xw, (const float4*)ex, (const float4*)denom,
                                      rowstart, csr_src,
                                      bias + (size_t)l * HD, gamma + (size_t)l * HD,
                                      beta + (size_t)l * HD, hin, hout);
        bf16* tmp = hin; hin = hout; hout = tmp;
    }

    // ---- pooling + output projection (bf16 MFMA, fp32 out) ----
    pool_k<<<BB, 256, 0, stream>>>(hin, bv, hg);
    gemm_bf16_k<false, false><<<dim3(HD / 128, BB / 128), 256, 0, stream>>>(
        hg, Wt3 + (size_t)2 * HD * HD, out, nullptr, out_b);
}

// Round 6
// 883.884 us; speedup vs baseline: 3.2161x; 1.2302x over previous
//
#include <hip/hip_runtime.h>
#include <hip/hip_bf16.h>

// Problem constants (match reference)
constexpr int NN  = 65536;           // nodes
constexpr int EE  = 262144;          // edges before self loops
constexpr int E2  = EE + NN;         // 327680 edges with self loops
constexpr int BB  = 2048;            // graphs
constexpr int HH  = 4;               // heads
constexpr int DD  = 192;             // per-head dim
constexpr int HD  = 768;             // hidden
constexpr int LL  = 2;               // layers
constexpr float EPS = 1e-5f;
constexpr float SLOPE = 0.2f;

typedef __attribute__((ext_vector_type(8))) short short8;   // 8 bf16 (4 VGPRs)
typedef __attribute__((ext_vector_type(4))) float f32x4;    // MFMA C/D
typedef __hip_bfloat16 bf16;

// ---------------------------------------------------------------------------
__global__ void zero_k(float* __restrict__ p, int n) {
    int i = blockIdx.x * 256 + threadIdx.x;
    if (i < n) p[i] = 0.f;
}

// fp32 -> bf16 convert (4 elements/thread)
__global__ void conv_k(const float4* __restrict__ src, bf16* __restrict__ dst, int n4) {
    int i = blockIdx.x * 256 + threadIdx.x;
    if (i >= n4) return;
    float4 v = src[i];
    bf16* o = dst + (size_t)i * 4;
    o[0] = __float2bfloat16(v.x); o[1] = __float2bfloat16(v.y);
    o[2] = __float2bfloat16(v.z); o[3] = __float2bfloat16(v.w);
}

// All 3 weight matrices (W0, W1, out_w): [k][n] fp32 -> [n][k] bf16, one dispatch
__global__ __launch_bounds__(256) void wconv3_k(const float* __restrict__ W,
                                                const float* __restrict__ OW,
                                                bf16* __restrict__ Wt3) {
    __shared__ float tile[32][33];
    const float* src = (blockIdx.z < 2) ? (W + (size_t)blockIdx.z * HD * HD) : OW;
    bf16* dst = Wt3 + (size_t)blockIdx.z * HD * HD;
    int bx = blockIdx.x * 32;   // n base
    int by = blockIdx.y * 32;   // k base
    int tx = threadIdx.x & 31, ty = threadIdx.x >> 5;   // ty 0..7
    #pragma unroll
    for (int r = 0; r < 32; r += 8)
        tile[ty + r][tx] = src[(size_t)(by + ty + r) * HD + bx + tx];
    __syncthreads();
    #pragma unroll
    for (int r = 0; r < 32; r += 8)
        dst[(size_t)(bx + ty + r) * HD + by + tx] = __float2bfloat16(tile[tx][ty + r]);
}

// ---------------------------------------------------------------------------
// bf16 MFMA GEMM: C[M,768] = A[M,768] @ Bt[768,768]^T
// A, Bt bf16 row-major [row][k]. Tile 128x128, BK=32, 256 thr (4 waves),
// each wave 4x4 grid of 16x16x32 MFMA. global_load_lds width-16 staging (m97).
// SWIZ: XCD-aware flat-grid swizzle for the 512x6 block grid.
__device__ __forceinline__ void load16_lds(const void* g, void* l) {
    __builtin_amdgcn_global_load_lds(
        (const __attribute__((address_space(1))) unsigned int*)g,
        (__attribute__((address_space(3))) unsigned int*)l, 16, 0, 0);
}

template <bool BF16_OUT, bool SWIZ>
__global__ __launch_bounds__(256) void gemm_bf16_k(
    const bf16* __restrict__ A, const bf16* __restrict__ Bt,
    float* __restrict__ Cf, bf16* __restrict__ Cb, const float* __restrict__ bias)
{
    constexpr int K = HD;
    __shared__ __attribute__((aligned(16))) short As[128 * 32];
    __shared__ __attribute__((aligned(16))) short Bs[128 * 32];

    int bx, by;
    if (SWIZ) {
        int gid = blockIdx.x;            // flat 3072 = 8 XCD * 8 sg * 48
        int xcd = gid & 7, lid = gid >> 3;   // lid 0..383
        int sg = lid / 48, sl = lid - sg * 48;
        by = (xcd << 6) + (sg << 3) + (sl & 7);   // row strip 0..511
        bx = sl >> 3;                              // col 0..5
    } else {
        bx = blockIdx.x; by = blockIdx.y;
    }

    int tid  = threadIdx.x;
    int wave = tid >> 6, lane = tid & 63;
    int wy = wave >> 1, wx = wave & 1;          // wave quadrant (64x64)
    int m16 = lane & 15, quad = lane >> 4;      // MFMA fragment coords
    int bm = by * 128;
    int bn = bx * 128;

    // staging positions: p = wave*128 + t*64 + lane -> chunk (row=p>>2, c=p&3)
    int p0 = wave * 128 + lane;                  // t=0
    int r0 = p0 >> 2, c0 = p0 & 3;
    int p1 = p0 + 64;                            // t=1
    int r1 = p1 >> 2, c1 = p1 & 3;

    const bf16* gA0 = A  + (size_t)(bm + r0) * K + c0 * 8;
    const bf16* gA1 = A  + (size_t)(bm + r1) * K + c1 * 8;
    const bf16* gB0 = Bt + (size_t)(bn + r0) * K + c0 * 8;
    const bf16* gB1 = Bt + (size_t)(bn + r1) * K + c1 * 8;

    f32x4 acc[4][4];
    #pragma unroll
    for (int i = 0; i < 4; i++)
        #pragma unroll
        for (int j = 0; j < 4; j++) acc[i][j] = (f32x4)0.f;

    const short8* Ac = (const short8*)As;
    const short8* Bc = (const short8*)Bs;

    for (int k0 = 0; k0 < K; k0 += 32) {
        load16_lds(gA0 + k0, &As[p0 * 8]);
        load16_lds(gA1 + k0, &As[p1 * 8]);
        load16_lds(gB0 + k0, &Bs[p0 * 8]);
        load16_lds(gB1 + k0, &Bs[p1 * 8]);
        __syncthreads();   // drains vmcnt(0): LDS tiles ready

        short8 a[4], b[4];
        #pragma unroll
        for (int i = 0; i < 4; i++)
            a[i] = Ac[(wy * 64 + i * 16 + m16) * 4 + quad];
        #pragma unroll
        for (int j = 0; j < 4; j++)
            b[j] = Bc[(wx * 64 + j * 16 + m16) * 4 + quad];
        #pragma unroll
        for (int i = 0; i < 4; i++)
            #pragma unroll
            for (int j = 0; j < 4; j++)
                acc[i][j] = __builtin_amdgcn_mfma_f32_16x16x32_bf16(a[i], b[j], acc[i][j], 0, 0, 0);
        __syncthreads();   // all ds_reads done before next staging overwrites
    }

    // epilogue: C/D layout col=lane&15, row=(lane>>4)*4+reg
    #pragma unroll
    for (int j = 0; j < 4; j++) {
        int col = bn + wx * 64 + j * 16 + m16;
        float badd = (!BF16_OUT && bias) ? bias[col] : 0.f;
        #pragma unroll
        for (int i = 0; i < 4; i++) {
            int row0 = bm + wy * 64 + i * 16 + quad * 4;
            #pragma unroll
            for (int r = 0; r < 4; r++) {
                if (BF16_OUT)
                    Cb[(size_t)(row0 + r) * HD + col] = __float2bfloat16(acc[i][j][r]);
                else
                    Cf[(size_t)(row0 + r) * HD + col] = acc[i][j][r] + badd;
            }
        }
    }
}

// ---------------------------------------------------------------------------
// per-node attention logits: asrc[n][h] = dot(xw[n,h,:], att_src[h,:]).
// One block per node, wave h handles head h; lanes 0..47 load 4 ch (uint2).
__device__ __forceinline__ float bflo(unsigned u) { return __uint_as_float(u << 16); }
__device__ __forceinline__ float bfhi(unsigned u) { return __uint_as_float(u & 0xffff0000u); }

__global__ __launch_bounds__(256) void alpha_k(
    const bf16* __restrict__ xw,
    const float* __restrict__ asl, const float* __restrict__ adl,
    float* __restrict__ asrc, float* __restrict__ adst)
{
    int n = blockIdx.x, t = threadIdx.x;
    int head = t >> 6, lane = t & 63;
    float s1 = 0.f, s2 = 0.f;
    if (lane < 48) {
        int c = head * DD + lane * 4;
        uint2 u = *(const uint2*)(xw + (size_t)n * HD + c);
        float4 a1 = *(const float4*)(asl + c);
        float4 a2 = *(const float4*)(adl + c);
        float v0 = bflo(u.x), v1 = bfhi(u.x), v2 = bflo(u.y), v3 = bfhi(u.y);
        s1 = v0 * a1.x + v1 * a1.y + v2 * a1.z + v3 * a1.w;
        s2 = v0 * a2.x + v1 * a2.y + v2 * a2.z + v3 * a2.w;
    }
    #pragma unroll
    for (int off = 32; off > 0; off >>= 1) {
        s1 += __shfl_down(s1, off, 64);
        s2 += __shfl_down(s2, off, 64);
    }
    if (lane == 0) {
        asrc[(size_t)n * HH + head] = s1;
        adst[(size_t)n * HH + head] = s2;
    }
}

// ---------------------------------------------------------------------------
// CSR build over dst
__global__ void hist_k(const int* __restrict__ ei, int* __restrict__ deg) {
    int e = blockIdx.x * 256 + threadIdx.x;   // grid == E2 exactly
    int dst = (e < EE) ? ei[EE + e] : (e - EE);
    atomicAdd(&deg[dst], 1);
}

__global__ void scan1_k(const int* __restrict__ deg, int* __restrict__ incl,
                        int* __restrict__ blocksum) {
    __shared__ int s[256];
    int t = threadIdx.x, n = blockIdx.x * 256 + t;
    int v = deg[n];
    s[t] = v;
    for (int off = 1; off < 256; off <<= 1) {
        __syncthreads();
        int tmp = (t >= off) ? s[t - off] : 0;
        __syncthreads();
        s[t] += tmp;
    }
    incl[n] = s[t];
    if (t == 255) blocksum[blockIdx.x] = s[255];
}

__global__ void scan2_k(const int* __restrict__ blocksum, int* __restrict__ blockoff) {
    __shared__ int s[256];
    int t = threadIdx.x;
    int v = blocksum[t];
    s[t] = v;
    for (int off = 1; off < 256; off <<= 1) {
        __syncthreads();
        int tmp = (t >= off) ? s[t - off] : 0;
        __syncthreads();
        s[t] += tmp;
    }
    blockoff[t] = s[t] - v;   // exclusive
}

__global__ void scan3_k(const int* __restrict__ deg, const int* __restrict__ blockoff,
                        int* __restrict__ incl_cursor, int* __restrict__ rowstart) {
    int t = threadIdx.x, n = blockIdx.x * 256 + t;
    int rs = blockoff[blockIdx.x] + incl_cursor[n] - deg[n];
    rowstart[n] = rs;
    incl_cursor[n] = rs;       // becomes the fill cursor
    if (n == 0) rowstart[NN] = E2;
}

__global__ void fill_k(const int* __restrict__ ei, int* __restrict__ cursor,
                       int* __restrict__ csr_src) {
    int e = blockIdx.x * 256 + threadIdx.x;
    int src = (e < EE) ? ei[e] : (e - EE);
    int dst = (e < EE) ? ei[EE + e] : (e - EE);
    int pos = atomicAdd(&cursor[dst], 1);
    csr_src[pos] = src;
}

// ---------------------------------------------------------------------------
// Fused GAT aggregation: edge softmax (no max-shift: logits are O(1), softmax
// is shift-invariant; denominator folded out by linearity) + attention-weighted
// gather + bias + LayerNorm + ReLU + residual. ONE WAVE PER NODE, 4 nodes per
// block, ZERO barriers (per-wave LDS slab; same-wave ds_write->ds_read only
// needs lgkmcnt). Lane owns 12 contiguous channels (3x uint2 = 24B, single
// head since 192/12=16 lanes/head).
__global__ __launch_bounds__(256) void agg_k(
    const bf16* __restrict__ xw, const float4* __restrict__ asrc,
    const float4* __restrict__ adst, const int* __restrict__ rowstart,
    const int* __restrict__ csr_src,
    const float* __restrict__ bias_l, const float* __restrict__ gamma_l,
    const float* __restrict__ beta_l, const bf16* __restrict__ h_in,
    bf16* __restrict__ h_out)
{
    __shared__ float s_w[4][64][4];   // per-wave edge weights (4 heads)
    __shared__ int   s_src[4][64];    // per-wave edge sources

    int wave = threadIdx.x >> 6, lane = threadIdx.x & 63;
    int i = blockIdx.x * 4 + wave;    // node
    int c = lane * 12;                // channel base
    int myhead = lane >> 4;           // 16 lanes per head

    int r0 = rowstart[i], r1 = rowstart[i + 1];
    float4 ad = adst[i];

    float acc[12];
    #pragma unroll
    for (int k = 0; k < 12; k++) acc[k] = 0.f;
    float4 den = make_float4(0.f, 0.f, 0.f, 0.f);

    for (int base = r0; base < r1; base += 64) {
        int cnt = min(64, r1 - base);
        float4 w4 = make_float4(0.f, 0.f, 0.f, 0.f);
        if (lane < cnt) {
            int s = csr_src[base + lane];
            s_src[wave][lane] = s;
            float4 a = asrc[s];                       // L2-resident gather
            float t0 = a.x + ad.x; t0 = (t0 > 0.f) ? t0 : SLOPE * t0;
            float t1 = a.y + ad.y; t1 = (t1 > 0.f) ? t1 : SLOPE * t1;
            float t2 = a.z + ad.z; t2 = (t2 > 0.f) ? t2 : SLOPE * t2;
            float t3 = a.w + ad.w; t3 = (t3 > 0.f) ? t3 : SLOPE * t3;
            w4 = make_float4(__expf(t0), __expf(t1), __expf(t2), __expf(t3));
            *(float4*)&s_w[wave][lane][0] = w4;
        }
        den.x += w4.x; den.y += w4.y; den.z += w4.z; den.w += w4.w;
        for (int e = 0; e < cnt; e++) {
            int src = __builtin_amdgcn_readfirstlane(s_src[wave][e]);
            float wv = s_w[wave][e][myhead];          // broadcast read
            const bf16* row = xw + (size_t)src * HD + c;
            uint2 u0 = *(const uint2*)(row);
            uint2 u1 = *(const uint2*)(row + 4);
            uint2 u2 = *(const uint2*)(row + 8);
            acc[0] += wv * bflo(u0.x); acc[1]  += wv * bfhi(u0.x);
            acc[2] += wv * bflo(u0.y); acc[3]  += wv * bfhi(u0.y);
            acc[4] += wv * bflo(u1.x); acc[5]  += wv * bfhi(u1.x);
            acc[6] += wv * bflo(u1.y); acc[7]  += wv * bfhi(u1.y);
            acc[8] += wv * bflo(u2.x); acc[9]  += wv * bfhi(u2.x);
            acc[10] += wv * bflo(u2.y); acc[11] += wv * bfhi(u2.y);
        }
    }

    // wave-allreduce denominator (butterfly), select my head's inverse
    #pragma unroll
    for (int off = 32; off > 0; off >>= 1) {
        den.x += __shfl_xor(den.x, off, 64);
        den.y += __shfl_xor(den.y, off, 64);
        den.z += __shfl_xor(den.z, off, 64);
        den.w += __shfl_xor(den.w, off, 64);
    }
    float deni = (myhead == 0) ? den.x : (myhead == 1) ? den.y
               : (myhead == 2) ? den.z : den.w;
    float inv = 1.f / deni;

    float4 b0 = *(const float4*)(bias_l + c);
    float4 b1 = *(const float4*)(bias_l + c + 4);
    float4 b2 = *(const float4*)(bias_l + c + 8);
    float v[12];
    v[0] = acc[0] * inv + b0.x; v[1]  = acc[1] * inv + b0.y;
    v[2] = acc[2] * inv + b0.z; v[3]  = acc[3] * inv + b0.w;
    v[4] = acc[4] * inv + b1.x; v[5]  = acc[5] * inv + b1.y;
    v[6] = acc[6] * inv + b1.z; v[7]  = acc[7] * inv + b1.w;
    v[8] = acc[8] * inv + b2.x; v[9]  = acc[9] * inv + b2.y;
    v[10] = acc[10] * inv + b2.z; v[11] = acc[11] * inv + b2.w;

    float s = 0.f;
    #pragma unroll
    for (int k = 0; k < 12; k++) s += v[k];
    #pragma unroll
    for (int off = 32; off > 0; off >>= 1) s += __shfl_xor(s, off, 64);
    float mean = s * (1.f / (float)HD);

    float q = 0.f;
    #pragma unroll
    for (int k = 0; k < 12; k++) { float d = v[k] - mean; q += d * d; }
    #pragma unroll
    for (int off = 32; off > 0; off >>= 1) q += __shfl_xor(q, off, 64);
    float rs = rsqrtf(q * (1.f / (float)HD) + EPS);

    float4 g0 = *(const float4*)(gamma_l + c);
    float4 g1 = *(const float4*)(gamma_l + c + 4);
    float4 g2 = *(const float4*)(gamma_l + c + 8);
    float4 e0 = *(const float4*)(beta_l + c);
    float4 e1 = *(const float4*)(beta_l + c + 4);
    float4 e2 = *(const float4*)(beta_l + c + 8);
    float gg[12] = {g0.x,g0.y,g0.z,g0.w,g1.x,g1.y,g1.z,g1.w,g2.x,g2.y,g2.z,g2.w};
    float bb[12] = {e0.x,e0.y,e0.z,e0.w,e1.x,e1.y,e1.z,e1.w,e2.x,e2.y,e2.z,e2.w};

    const bf16* hrow = h_in + (size_t)i * HD + c;
    uint2 hu0 = *(const uint2*)(hrow);
    uint2 hu1 = *(const uint2*)(hrow + 4);
    uint2 hu2 = *(const uint2*)(hrow + 8);
    float hres[12] = {bflo(hu0.x), bfhi(hu0.x), bflo(hu0.y), bfhi(hu0.y),
                      bflo(hu1.x), bfhi(hu1.x), bflo(hu1.y), bfhi(hu1.y),
                      bflo(hu2.x), bfhi(hu2.x), bflo(hu2.y), bfhi(hu2.y)};

    bf16 pk[12];
    #pragma unroll
    for (int k = 0; k < 12; k++) {
        float o = fmaxf((v[k] - mean) * rs * gg[k] + bb[k], 0.f) + hres[k];
        pk[k] = __float2bfloat16(o);
    }
    bf16* orow = h_out + (size_t)i * HD + c;
    *(uint2*)(orow)     = *(const uint2*)&pk[0];
    *(uint2*)(orow + 4) = *(const uint2*)&pk[4];
    *(uint2*)(orow + 8) = *(const uint2*)&pk[8];
}

// ---------------------------------------------------------------------------
// global mean pool per graph -> bf16 hg; 192 threads, 4 ch/thread (uint2)
__global__ __launch_bounds__(192) void pool_k(
    const bf16* __restrict__ h, const int* __restrict__ bv,
    bf16* __restrict__ hg)
{
    int g = blockIdx.x, t = threadIdx.x;
    int lo = 0, hi = NN;
    while (lo < hi) { int mid = (lo + hi) >> 1; if (bv[mid] < g) lo = mid + 1; else hi = mid; }
    int start = lo;
    hi = NN;
    while (lo < hi) { int mid = (lo + hi) >> 1; if (bv[mid] < g + 1) lo = mid + 1; else hi = mid; }
    int end = lo;
    int c = t * 4;
    float a0 = 0.f, a1 = 0.f, a2 = 0.f, a3 = 0.f;
    for (int n = start; n < end; n++) {
        uint2 u = *(const uint2*)(h + (size_t)n * HD + c);
        a0 += bflo(u.x); a1 += bfhi(u.x); a2 += bflo(u.y); a3 += bfhi(u.y);
    }
    float sc = 1.f / fmaxf((float)(end - start), 1.f);
    bf16 pk[4];
    pk[0] = __float2bfloat16(a0 * sc); pk[1] = __float2bfloat16(a1 * sc);
    pk[2] = __float2bfloat16(a2 * sc); pk[3] = __float2bfloat16(a3 * sc);
    *(uint2*)(hg + (size_t)g * HD + c) = *(const uint2*)pk;
}

// ---------------------------------------------------------------------------
extern "C" void kernel_launch(void* const* d_in, const int* in_sizes, int n_in,
                              void* d_out, int out_size, void* d_ws, size_t ws_size,
                              hipStream_t stream)
{
    (void)in_sizes; (void)n_in; (void)out_size; (void)ws_size;
    const float* x       = (const float*)d_in[0];
    const int*   ei      = (const int*)d_in[1];
    const int*   bv      = (const int*)d_in[2];
    const float* W       = (const float*)d_in[3];
    const float* att_src = (const float*)d_in[4];
    const float* att_dst = (const float*)d_in[5];
    const float* bias    = (const float*)d_in[6];
    const float* gamma   = (const float*)d_in[7];
    const float* beta    = (const float*)d_in[8];
    const float* out_w   = (const float*)d_in[9];
    const float* out_b   = (const float*)d_in[10];
    float* out = (float*)d_out;

    char* p = (char*)d_ws;
    size_t off = 0;
    auto take = [&](size_t bytes) -> char* {
        char* r = p + off;
        off = (off + bytes + 255) & ~(size_t)255;
        return r;
    };
    bf16* xw        = (bf16*)take((size_t)NN * HD * 2);   // bf16 projected feats
    bf16* hbf0      = (bf16*)take((size_t)NN * HD * 2);   // h ping
    bf16* hbf1      = (bf16*)take((size_t)NN * HD * 2);   // h pong
    bf16* Wt3       = (bf16*)take((size_t)3 * HD * HD * 2); // W0,W1,out_w bf16^T
    float* asrc     = (float*)take((size_t)NN * HH * 4);
    float* adst     = (float*)take((size_t)NN * HH * 4);
    int*   deg      = (int*)take((size_t)NN * 4);
    int*   rowstart = (int*)take((size_t)(NN + 1) * 4);
    int*   cursor   = (int*)take((size_t)NN * 4);
    int*   blocksum = (int*)take(256 * 4);
    int*   blockoff = (int*)take(256 * 4);
    int*   csr_src  = (int*)take((size_t)E2 * 4);
    bf16*  hg       = (bf16*)take((size_t)BB * HD * 2);

    const int EB = E2 / 256;   // 1280, exact

    // ---- CSR build (topology only, once) ----
    zero_k<<<NN / 256, 256, 0, stream>>>((float*)deg, NN);
    hist_k<<<EB, 256, 0, stream>>>(ei, deg);
    scan1_k<<<NN / 256, 256, 0, stream>>>(deg, cursor, blocksum);
    scan2_k<<<1, 256, 0, stream>>>(blocksum, blockoff);
    scan3_k<<<NN / 256, 256, 0, stream>>>(deg, blockoff, cursor, rowstart);
    fill_k<<<EB, 256, 0, stream>>>(ei, cursor, csr_src);

    // ---- bf16 conversions ----
    conv_k<<<(NN * HD / 4 + 255) / 256, 256, 0, stream>>>((const float4*)x, hbf0, NN * HD / 4);
    wconv3_k<<<dim3(HD / 32, HD / 32, 3), 256, 0, stream>>>(W, out_w, Wt3);

    // ---- layers (ping-pong h buffers) ----
    bf16* hin = hbf0;
    bf16* hout = hbf1;
    for (int l = 0; l < LL; l++) {
        gemm_bf16_k<true, true><<<3072, 256, 0, stream>>>(
            hin, Wt3 + (size_t)l * HD * HD, nullptr, xw, nullptr);
        alpha_k<<<NN, 256, 0, stream>>>(xw, att_src + (size_t)l * HH * DD,
                                        att_dst + (size_t)l * HH * DD, asrc, adst);
        agg_k<<<NN / 4, 256, 0, stream>>>(xw, (const float4*)asrc, (const float4*)adst,
                                          rowstart, csr_src,
                                          bias + (size_t)l * HD, gamma + (size_t)l * HD,
                                          beta + (size_t)l * HD, hin, hout);
        bf16* tmp = hin; hin = hout; hout = tmp;
    }

    // ---- pooling + output projection (bf16 MFMA, fp32 out) ----
    pool_k<<<BB, 192, 0, stream>>>(hin, bv, hg);
    gemm_bf16_k<false, false><<<dim3(HD / 128, BB / 128), 256, 0, stream>>>(
        hg, Wt3 + (size_t)2 * HD * HD, out, nullptr, out_b);
}